// Round 9
// baseline (404.188 us; speedup 1.0000x reference)
//
#include <hip/hip_runtime.h>
#include <hip/hip_bf16.h>
#include <math.h>

// N=50000 nodes, E=800000 edges, D=128, F_IN=8, C=2
// Output float32: [probs E*2 | bbox_pairs E*8 | bbox_index_pairs E*2]

typedef __attribute__((ext_vector_type(8))) short short8;
typedef __attribute__((ext_vector_type(4))) float f32x4;
typedef __attribute__((ext_vector_type(16))) float f32x16;

__device__ inline ushort f2bf(float f) {
    union { __hip_bfloat16 h; ushort u; } cv;
    cv.h = __float2bfloat16(f);
    return cv.u;
}
__device__ inline float bf2f(ushort u) {
    union { float f; uint u; } c;
    c.u = ((uint)u) << 16;
    return c.f;
}

// ---------------- CSR build ----------------
__global__ void k_hist(const int* __restrict__ col, int* __restrict__ cnt, int E) {
    int e = blockIdx.x * blockDim.x + threadIdx.x;
    if (e < E) atomicAdd(&cnt[col[e]], 1);
}

__global__ __launch_bounds__(1024) void k_scan(const int* __restrict__ cnt,
                                               int* __restrict__ ptr, int N) {
    __shared__ int sums[1024];
    int tid = threadIdx.x;
    int chunk = (N + 1023) / 1024;
    int lo = tid * chunk;
    int hi = min(lo + chunk, N);
    int s = 0;
    for (int i = lo; i < hi; ++i) s += cnt[i];
    sums[tid] = s;
    __syncthreads();
    for (int off = 1; off < 1024; off <<= 1) {
        int v = (tid >= off) ? sums[tid - off] : 0;
        __syncthreads();
        sums[tid] += v;
        __syncthreads();
    }
    int run = (tid > 0) ? sums[tid - 1] : 0;
    for (int i = lo; i < hi; ++i) { ptr[i] = run; run += cnt[i]; }
    if (tid == 1023) ptr[N] = run;
}

// fill CSR; norm computed inline from final cnt (deg = cnt, self-loop adds 1)
__global__ void k_fill(const int* __restrict__ row, const int* __restrict__ col,
                       const int* __restrict__ cnt, const int* __restrict__ ptr,
                       int* __restrict__ cursor, int* __restrict__ esrc,
                       float* __restrict__ enorm, int E) {
    int e = blockIdx.x * blockDim.x + threadIdx.x;
    if (e >= E) return;
    int r = row[e], c = col[e];
    float dr = rsqrtf(1.0f + (float)cnt[r]);
    float dc = rsqrtf(1.0f + (float)cnt[c]);
    int p = ptr[c] + atomicAdd(&cursor[c], 1);
    esrc[p] = r;
    enorm[p] = dr * dc;
}

// ---------------- weight prep ----------------
__global__ void k_prepW(const float* __restrict__ W, ushort* __restrict__ Wt) {
    int tid = blockIdx.x * blockDim.x + threadIdx.x;
    if (tid >= 128 * 256) return;
    int n = tid >> 8, k = tid & 255;
    Wt[tid] = f2bf(W[k * 128 + n]);
}
__global__ void k_prepW2(const float* __restrict__ W, ushort* __restrict__ Wt) {
    int tid = blockIdx.x * blockDim.x + threadIdx.x;
    if (tid >= 128 * 128) return;
    int n = tid >> 7, k = tid & 127;
    Wt[tid] = f2bf(W[k * 128 + n]);
}

// ---------------- layer-1 aggregate on raw features [N,8] ----------------
__global__ __launch_bounds__(256) void k_agg8(const float* __restrict__ feat,
                                              const int* __restrict__ cnt,
                                              const int* __restrict__ ptr,
                                              const int* __restrict__ esrc,
                                              const float* __restrict__ enorm,
                                              float* __restrict__ aggF, int N) {
    int lane8 = threadIdx.x & 7;
    int node = blockIdx.x * 32 + (threadIdx.x >> 3);
    if (node >= N) return;
    float dd = 1.0f / (1.0f + (float)cnt[node]);
    float acc = feat[(size_t)node * 8 + lane8] * dd;
    int i = ptr[node], end = ptr[node + 1];
    for (; i < end; ++i) {
        acc += feat[(size_t)esrc[i] * 8 + lane8] * enorm[i];
    }
    aggF[(size_t)node * 8 + lane8] = acc;
}

// ---------------- layer-1 GEMM: x1 = bf16(relu(aggF[N,8] @ W1 + b1)) ----------------
__global__ __launch_bounds__(256) void k_gemm1(const float* __restrict__ aggF,
                                               const float* __restrict__ W1,
                                               const float* __restrict__ b1,
                                               ushort* __restrict__ x1, int total) {
    int tid = blockIdx.x * blockDim.x + threadIdx.x;
    if (tid >= total) return;
    int n = tid >> 7, j = tid & 127;
    float acc = b1[j];
#pragma unroll
    for (int k = 0; k < 8; ++k) acc += aggF[(size_t)n * 8 + k] * W1[k * 128 + j];
    x1[tid] = f2bf(fmaxf(acc, 0.f));
}

// ---------------- layer-2 GEMM via MFMA: h2 = x1[N,128] @ W2 (bf16 out) ----------------
// Block: 256 thr = 4 waves, 64 nodes. Wave: 16 nodes x 128 cols, K=128.  (R5 shape)
__global__ __launch_bounds__(256) void k_gemm2(const ushort* __restrict__ x1,
                                               const ushort* __restrict__ W2t,
                                               ushort* __restrict__ h2, int N) {
    __shared__ ushort ldsW[128 * 128];   // 32 KB, XOR-swizzled (256B rows)
    const int tid = threadIdx.x;
    const int wave = tid >> 6, lane = tid & 63;
    const int m = lane & 15, kb = lane >> 4;
    const int n0 = blockIdx.x * 64;

    const int node_a = min(n0 + wave * 16 + m, N - 1);
    short8 a[4];
#pragma unroll
    for (int kk = 0; kk < 4; ++kk) {
        a[kk] = *reinterpret_cast<const short8*>(&x1[(size_t)node_a * 128 + kk * 32 + kb * 8]);
    }

    {
        char* lb = reinterpret_cast<char*>(ldsW);
        const short8* wg = reinterpret_cast<const short8*>(W2t);
#pragma unroll
        for (int i = 0; i < 8; ++i) {
            const int g = i * 256 + tid;
            const int bo = g * 16;
            const int swz = bo ^ (((bo >> 8) & 7) << 4);
            *reinterpret_cast<short8*>(lb + swz) = wg[g];
        }
    }
    __syncthreads();

    f32x4 acc[8];
#pragma unroll
    for (int t = 0; t < 8; ++t) acc[t] = (f32x4){0.f, 0.f, 0.f, 0.f};

    const char* lbr = reinterpret_cast<const char*>(ldsW);
    const int mswz = (m & 7) << 4;
#pragma unroll
    for (int kk = 0; kk < 4; ++kk) {
#pragma unroll
        for (int t = 0; t < 8; ++t) {
            const int bo = (t * 16 + m) * 256 + kk * 64 + kb * 16;
            const short8 b = *reinterpret_cast<const short8*>(lbr + (bo ^ mswz));
            acc[t] = __builtin_amdgcn_mfma_f32_16x16x32_bf16(a[kk], b, acc[t], 0, 0, 0);
        }
    }

    // C layout: col = t*16 + m, row(node) = kb*4 + r
#pragma unroll
    for (int r = 0; r < 4; ++r) {
        const int node = n0 + wave * 16 + kb * 4 + r;
        if (node < N) {
#pragma unroll
            for (int t = 0; t < 8; ++t) {
                h2[(size_t)node * 128 + t * 16 + m] = f2bf(acc[t][r]);
            }
        }
    }
}

// ---------------- layer-2 aggregate (R5 shape: 16 lanes/node, short8/lane) ----------------
__global__ __launch_bounds__(256) void k_gather2(const ushort* __restrict__ h2,
                                                 const int* __restrict__ cnt,
                                                 const int* __restrict__ ptr,
                                                 const int* __restrict__ esrc,
                                                 const float* __restrict__ enorm,
                                                 const float* __restrict__ b2,
                                                 ushort* __restrict__ xbf, int N) {
    int lane16 = threadIdx.x & 15;
    int node = blockIdx.x * 16 + (threadIdx.x >> 4);
    if (node >= N) return;
    float dd = 1.0f / (1.0f + (float)cnt[node]);
    float acc[8];
    {
        const short8 v = *reinterpret_cast<const short8*>(&h2[(size_t)node * 128 + lane16 * 8]);
#pragma unroll
        for (int i = 0; i < 8; ++i) acc[i] = bf2f((ushort)v[i]) * dd;
    }
    int i = ptr[node], end = ptr[node + 1];
    for (; i < end; ++i) {
        const int s = esrc[i];
        const float nm = enorm[i];
        const short8 v = *reinterpret_cast<const short8*>(&h2[(size_t)s * 128 + lane16 * 8]);
#pragma unroll
        for (int q = 0; q < 8; ++q) acc[q] += bf2f((ushort)v[q]) * nm;
    }
    short8 r;
#pragma unroll
    for (int q = 0; q < 8; ++q) {
        r[q] = (short)f2bf(fmaxf(acc[q] + b2[lane16 * 8 + q], 0.f));
    }
    *reinterpret_cast<short8*>(&xbf[(size_t)node * 128 + lane16 * 8]) = r;
}

// ---------------- edge MLP via 32x32x16 MFMA, LDS-staged weights ----------------
// Block: 512 threads = 8 waves, 256 edges. Wave: 32 edges x 128 hidden, K=256,
// A loaded in two 8-step phases (src rows, then dst rows) to cap VGPRs.
#define EB2 256
__global__ __launch_bounds__(512, 4) void k_edge_mfma(const ushort* __restrict__ xbf,
                                                      const ushort* __restrict__ Wt,
                                                      const float* __restrict__ lin1b,
                                                      const float* __restrict__ linfW,
                                                      const float* __restrict__ linfb,
                                                      const float* __restrict__ bboxes,
                                                      const int* __restrict__ bidx,
                                                      const int* __restrict__ row,
                                                      const int* __restrict__ col,
                                                      float* __restrict__ out_probs,
                                                      float* __restrict__ out_bbox,
                                                      float* __restrict__ out_bidx,
                                                      int E) {
    __shared__ ushort ldsW[128 * 256];   // 64 KB, XOR-swizzled (512B rows)
    const int tid = threadIdx.x;
    const int wave = tid >> 6, lane = tid & 63;
    const int e0 = blockIdx.x * EB2;
    const int el = lane & 31;        // edge within wave's 32 (A-row / B-col lane)
    const int h = lane >> 5;         // k-half selector
    const int ebase = e0 + wave * 32;

    const int ec = min(ebase + el, E - 1);
    const int src = row[ec], dst = col[ec];

    // Phase-1 A: src rows. lane: row=el, k = s*16 + h*8 .. +7 (elements)
    short8 a[8];
#pragma unroll
    for (int s = 0; s < 8; ++s) {
        a[s] = *reinterpret_cast<const short8*>(&xbf[(size_t)src * 128 + s * 16 + h * 8]);
    }

    // Stage Wt -> LDS (identical layout/swizzle to R5; B-read pattern verified even)
    {
        char* lb = reinterpret_cast<char*>(ldsW);
        const short8* wg = reinterpret_cast<const short8*>(Wt);
#pragma unroll
        for (int i = 0; i < 8; ++i) {
            const int g = i * 512 + tid;
            const int bo = g * 16;
            const int swz = bo ^ (((bo >> 9) & 7) << 4);
            *reinterpret_cast<short8*>(lb + swz) = wg[g];
        }
    }
    __syncthreads();

    f32x16 acc[4];
#pragma unroll
    for (int tq = 0; tq < 4; ++tq)
#pragma unroll
        for (int r = 0; r < 16; ++r) acc[tq][r] = 0.f;

    const char* lbr = reinterpret_cast<const char*>(ldsW);
    const int mswz = (lane & 7) << 4;

    // K steps 0..7 (src half)
#pragma unroll
    for (int s = 0; s < 8; ++s) {
#pragma unroll
        for (int tq = 0; tq < 4; ++tq) {
            const int bo = (tq * 32 + el) * 512 + s * 32 + h * 16;
            const short8 b = *reinterpret_cast<const short8*>(lbr + (bo ^ mswz));
            acc[tq] = __builtin_amdgcn_mfma_f32_32x32x16_bf16(a[s], b, acc[tq], 0, 0, 0);
        }
    }
    // Phase-2 A: dst rows (reuse registers)
#pragma unroll
    for (int s = 0; s < 8; ++s) {
        a[s] = *reinterpret_cast<const short8*>(&xbf[(size_t)dst * 128 + s * 16 + h * 8]);
    }
    // K steps 8..15 (dst half)
#pragma unroll
    for (int s = 0; s < 8; ++s) {
#pragma unroll
        for (int tq = 0; tq < 4; ++tq) {
            const int bo = (tq * 32 + el) * 512 + (s + 8) * 32 + h * 16;
            const short8 b = *reinterpret_cast<const short8*>(lbr + (bo ^ mswz));
            acc[tq] = __builtin_amdgcn_mfma_f32_32x32x16_bf16(a[s], b, acc[tq], 0, 0, 0);
        }
    }

    // Epilogue: bias+relu in-register; single logit-diff d = z0-z1 per edge.
    // C layout: col = tq*32 + el, row(edge) = (r&3) + 8*(r>>2) + 4*h.
    float pd[16];
#pragma unroll
    for (int r = 0; r < 16; ++r) pd[r] = 0.f;
#pragma unroll
    for (int tq = 0; tq < 4; ++tq) {
        const int c = tq * 32 + el;
        const float bn = lin1b[c];
        const float2 wf = *reinterpret_cast<const float2*>(&linfW[c * 2]);
        const float wd = wf.x - wf.y;
#pragma unroll
        for (int r = 0; r < 16; ++r) {
            const float hv = fmaxf(acc[tq][r] + bn, 0.f);
            pd[r] = fmaf(hv, wd, pd[r]);
        }
    }
    // reduce across the 32 col-lanes (xor bits 0..4; h preserved)
#pragma unroll
    for (int s = 1; s < 32; s <<= 1) {
#pragma unroll
        for (int r = 0; r < 16; ++r) pd[r] += __shfl_xor(pd[r], s);
    }

    if (el < 16) {
        // static-index selection tree: dsel = pd[el & 15]
        float q[8], rr[4], ss[2];
#pragma unroll
        for (int i = 0; i < 8; ++i) q[i] = (lane & 1) ? pd[2 * i + 1] : pd[2 * i];
#pragma unroll
        for (int i = 0; i < 4; ++i) rr[i] = (lane & 2) ? q[2 * i + 1] : q[2 * i];
#pragma unroll
        for (int i = 0; i < 2; ++i) ss[i] = (lane & 4) ? rr[2 * i + 1] : rr[2 * i];
        const float dsel = (lane & 8) ? ss[1] : ss[0];
        const int r = lane & 15;
        const int erow = (r & 3) + 8 * (r >> 2) + 4 * h;
        const int edge = ebase + erow;
        if (edge < E) {
            const float d = dsel + (linfb[0] - linfb[1]);  // z0 - z1
            const float ad = fabsf(d);
            const float t = -log1pf(expf(-ad));            // log-prob of the larger class
            const float2 pr = (d >= 0.f) ? make_float2(t, t - ad) : make_float2(t - ad, t);
            *reinterpret_cast<float2*>(&out_probs[(size_t)edge * 2]) = pr;
        }
    }

    // bbox_pairs [E,8] and bbox_index_pairs [E,2]
    for (int idx = tid; idx < EB2 * 8; idx += 512) {
        const int ee = idx >> 3, qq = idx & 7;
        const int e2 = e0 + ee;
        if (e2 < E) {
            const int node = (qq < 4) ? row[e2] : col[e2];
            out_bbox[(size_t)e2 * 8 + qq] = bboxes[(size_t)node * 4 + (qq & 3)];
        }
    }
    for (int idx = tid; idx < EB2 * 2; idx += 512) {
        const int ee = idx >> 1, c = idx & 1;
        const int e2 = e0 + ee;
        if (e2 < E) {
            const int node = c ? col[e2] : row[e2];
            out_bidx[(size_t)e2 * 2 + c] = (float)bidx[node];
        }
    }
}

extern "C" void kernel_launch(void* const* d_in, const int* in_sizes, int n_in,
                              void* d_out, int out_size, void* d_ws, size_t ws_size,
                              hipStream_t stream) {
    const float* feat   = (const float*)d_in[0];
    const float* bboxes = (const float*)d_in[1];
    const int*   bidx   = (const int*)d_in[2];
    const int*   eidx   = (const int*)d_in[3];
    const float* W1     = (const float*)d_in[4];
    const float* b1     = (const float*)d_in[5];
    const float* W2     = (const float*)d_in[6];
    const float* b2     = (const float*)d_in[7];
    const float* lin1W  = (const float*)d_in[8];
    const float* lin1b  = (const float*)d_in[9];
    const float* linfW  = (const float*)d_in[10];
    const float* linfb  = (const float*)d_in[11];

    const int N = in_sizes[0] / 8;
    const int E = in_sizes[3] / 2;
    const int* row = eidx;        // sources
    const int* col = eidx + E;    // targets

    size_t Np = ((size_t)N + 255) & ~255ull;
    size_t Ep = ((size_t)E + 255) & ~255ull;
    size_t A8 = (((size_t)N * 8) + 255) & ~255ull;
    int*    cnt    = (int*)d_ws;                 // Np
    int*    cursor = cnt + Np;                   // Np (zeroed together with cnt)
    int*    ptr    = cursor + Np;                // Np+256
    int*    esrc   = ptr + Np + 256;             // Ep
    float*  enorm  = (float*)(esrc + Ep);        // Ep
    float*  aggF   = enorm + Ep;                 // A8 f32
    ushort* x1     = (ushort*)(aggF + A8);       // N*128 bf16
    ushort* h2     = x1 + (size_t)N * 128;       // N*128 bf16
    ushort* xbf    = h2 + (size_t)N * 128;       // N*128 bf16
    ushort* Wt     = xbf + (size_t)N * 128;      // 128*256 bf16
    ushort* W2t    = Wt + 128 * 256;             // 128*128 bf16

    float* out       = (float*)d_out;
    float* out_probs = out;                   // E*2
    float* out_bbox  = out + (size_t)E * 2;   // E*8
    float* out_bidx  = out + (size_t)E * 10;  // E*2

    const int total = N * 128;
    const int B = 256;

    // CSR build + weight prep
    hipMemsetAsync(cnt, 0, 2 * Np * sizeof(int), stream);   // cnt + cursor
    k_hist<<<(E + B - 1) / B, B, 0, stream>>>(col, cnt, E);
    k_scan<<<1, 1024, 0, stream>>>(cnt, ptr, N);
    k_fill<<<(E + B - 1) / B, B, 0, stream>>>(row, col, cnt, ptr, cursor, esrc, enorm, E);
    k_prepW<<<(128 * 256 + B - 1) / B, B, 0, stream>>>(lin1W, Wt);
    k_prepW2<<<(128 * 128 + B - 1) / B, B, 0, stream>>>(W2, W2t);

    // layer 1 (aggregate-first on [N,8], then tiny GEMM)
    k_agg8<<<(N + 31) / 32, B, 0, stream>>>(feat, cnt, ptr, esrc, enorm, aggF, N);
    k_gemm1<<<(total + B - 1) / B, B, 0, stream>>>(aggF, W1, b1, x1, total);

    // layer 2 (MFMA GEMM, then 16-lane gather)
    k_gemm2<<<(N + 63) / 64, B, 0, stream>>>(x1, W2t, h2, N);
    k_gather2<<<(N + 15) / 16, B, 0, stream>>>(h2, cnt, ptr, esrc, enorm, b2, xbf, N);

    // edge MLP (32x32 MFMA, LDS weights) + outputs
    k_edge_mfma<<<(E + EB2 - 1) / EB2, 512, 0, stream>>>(xbf, Wt, lin1b, linfW, linfb,
                                                         bboxes, bidx, row, col,
                                                         out_probs, out_bbox, out_bidx, E);
}

// Round 10
// 334.910 us; speedup vs baseline: 1.2069x; 1.2069x over previous
//
#include <hip/hip_runtime.h>
#include <hip/hip_bf16.h>
#include <math.h>

// N=50000 nodes, E=800000 edges, D=128, F_IN=8, C=2
// Output float32: [probs E*2 | bbox_pairs E*8 | bbox_index_pairs E*2]

typedef __attribute__((ext_vector_type(8))) short short8;
typedef __attribute__((ext_vector_type(4))) float f32x4;

__device__ inline ushort f2bf(float f) {
    union { __hip_bfloat16 h; ushort u; } cv;
    cv.h = __float2bfloat16(f);
    return cv.u;
}
__device__ inline float bf2f(ushort u) {
    union { float f; uint u; } c;
    c.u = ((uint)u) << 16;
    return c.f;
}

// ---------------- CSR build ----------------
__global__ void k_hist(const int* __restrict__ col, int* __restrict__ cnt, int E) {
    int e = blockIdx.x * blockDim.x + threadIdx.x;
    if (e < E) atomicAdd(&cnt[col[e]], 1);
}

__global__ __launch_bounds__(1024) void k_scan(const int* __restrict__ cnt,
                                               int* __restrict__ ptr, int N) {
    __shared__ int sums[1024];
    int tid = threadIdx.x;
    int chunk = (N + 1023) / 1024;
    int lo = tid * chunk;
    int hi = min(lo + chunk, N);
    int s = 0;
    for (int i = lo; i < hi; ++i) s += cnt[i];
    sums[tid] = s;
    __syncthreads();
    for (int off = 1; off < 1024; off <<= 1) {
        int v = (tid >= off) ? sums[tid - off] : 0;
        __syncthreads();
        sums[tid] += v;
        __syncthreads();
    }
    int run = (tid > 0) ? sums[tid - 1] : 0;
    for (int i = lo; i < hi; ++i) { ptr[i] = run; run += cnt[i]; }
    if (tid == 1023) ptr[N] = run;
}

__global__ void k_fill(const int* __restrict__ row, const int* __restrict__ col,
                       const int* __restrict__ cnt, const int* __restrict__ ptr,
                       int* __restrict__ cursor, int* __restrict__ esrc,
                       float* __restrict__ enorm, int E) {
    int e = blockIdx.x * blockDim.x + threadIdx.x;
    if (e >= E) return;
    int r = row[e], c = col[e];
    float dr = rsqrtf(1.0f + (float)cnt[r]);
    float dc = rsqrtf(1.0f + (float)cnt[c]);
    int p = ptr[c] + atomicAdd(&cursor[c], 1);
    esrc[p] = r;
    enorm[p] = dr * dc;
}

// ---------------- weight prep ----------------
// Wuv[c][k], c<256, k<128:  c<128: W[k][c] (u = x*W_top) ; c>=128: W[128+k][c-128] (v = x*W_bot)
__global__ void k_prepWuv(const float* __restrict__ W, ushort* __restrict__ Wuv) {
    int tid = blockIdx.x * blockDim.x + threadIdx.x;
    if (tid >= 256 * 128) return;
    int c = tid >> 7, k = tid & 127;
    int krow = k + ((c >> 7) << 7);
    Wuv[tid] = f2bf(W[krow * 128 + (c & 127)]);
}
// W2t[n][k] = bf16(W2[k][n])
__global__ void k_prepW2(const float* __restrict__ W, ushort* __restrict__ Wt) {
    int tid = blockIdx.x * blockDim.x + threadIdx.x;
    if (tid >= 128 * 128) return;
    int n = tid >> 7, k = tid & 127;
    Wt[tid] = f2bf(W[k * 128 + n]);
}

// ---------------- layer-1 aggregate on raw features [N,8] ----------------
__global__ __launch_bounds__(256) void k_agg8(const float* __restrict__ feat,
                                              const int* __restrict__ cnt,
                                              const int* __restrict__ ptr,
                                              const int* __restrict__ esrc,
                                              const float* __restrict__ enorm,
                                              float* __restrict__ aggF, int N) {
    int lane8 = threadIdx.x & 7;
    int node = blockIdx.x * 32 + (threadIdx.x >> 3);
    if (node >= N) return;
    float dd = 1.0f / (1.0f + (float)cnt[node]);
    float acc = feat[(size_t)node * 8 + lane8] * dd;
    int i = ptr[node], end = ptr[node + 1];
    for (; i < end; ++i) {
        acc += feat[(size_t)esrc[i] * 8 + lane8] * enorm[i];
    }
    aggF[(size_t)node * 8 + lane8] = acc;
}

// ---------------- layer-1 GEMM: x1 = bf16(relu(aggF[N,8] @ W1 + b1)) ----------------
__global__ __launch_bounds__(256) void k_gemm1(const float* __restrict__ aggF,
                                               const float* __restrict__ W1,
                                               const float* __restrict__ b1,
                                               ushort* __restrict__ x1, int total) {
    int tid = blockIdx.x * blockDim.x + threadIdx.x;
    if (tid >= total) return;
    int n = tid >> 7, j = tid & 127;
    float acc = b1[j];
#pragma unroll
    for (int k = 0; k < 8; ++k) acc += aggF[(size_t)n * 8 + k] * W1[k * 128 + j];
    x1[tid] = f2bf(fmaxf(acc, 0.f));
}

// ---------------- layer-2 GEMM via MFMA: h2 = x1[N,128] @ W2 (bf16 out) ----------------
// Block: 256 thr = 4 waves, 64 nodes. Wave: 16 nodes x 128 cols, K=128.  (proven R5 shape)
__global__ __launch_bounds__(256) void k_gemm2(const ushort* __restrict__ x1,
                                               const ushort* __restrict__ W2t,
                                               ushort* __restrict__ h2, int N) {
    __shared__ ushort ldsW[128 * 128];   // 32 KB, XOR-swizzled (256B rows)
    const int tid = threadIdx.x;
    const int wave = tid >> 6, lane = tid & 63;
    const int m = lane & 15, kb = lane >> 4;
    const int n0 = blockIdx.x * 64;

    const int node_a = min(n0 + wave * 16 + m, N - 1);
    short8 a[4];
#pragma unroll
    for (int kk = 0; kk < 4; ++kk) {
        a[kk] = *reinterpret_cast<const short8*>(&x1[(size_t)node_a * 128 + kk * 32 + kb * 8]);
    }

    {
        char* lb = reinterpret_cast<char*>(ldsW);
        const short8* wg = reinterpret_cast<const short8*>(W2t);
#pragma unroll
        for (int i = 0; i < 8; ++i) {
            const int g = i * 256 + tid;
            const int bo = g * 16;
            const int swz = bo ^ (((bo >> 8) & 7) << 4);
            *reinterpret_cast<short8*>(lb + swz) = wg[g];
        }
    }
    __syncthreads();

    f32x4 acc[8];
#pragma unroll
    for (int t = 0; t < 8; ++t) acc[t] = (f32x4){0.f, 0.f, 0.f, 0.f};

    const char* lbr = reinterpret_cast<const char*>(ldsW);
    const int mswz = (m & 7) << 4;
#pragma unroll
    for (int kk = 0; kk < 4; ++kk) {
#pragma unroll
        for (int t = 0; t < 8; ++t) {
            const int bo = (t * 16 + m) * 256 + kk * 64 + kb * 16;
            const short8 b = *reinterpret_cast<const short8*>(lbr + (bo ^ mswz));
            acc[t] = __builtin_amdgcn_mfma_f32_16x16x32_bf16(a[kk], b, acc[t], 0, 0, 0);
        }
    }

#pragma unroll
    for (int r = 0; r < 4; ++r) {
        const int node = n0 + wave * 16 + kb * 4 + r;
        if (node < N) {
#pragma unroll
            for (int t = 0; t < 8; ++t) {
                h2[(size_t)node * 128 + t * 16 + m] = f2bf(acc[t][r]);
            }
        }
    }
}

// ---------------- layer-2 aggregate (16 lanes/node, short8/lane; proven R5 shape) ----------------
__global__ __launch_bounds__(256) void k_gather2(const ushort* __restrict__ h2,
                                                 const int* __restrict__ cnt,
                                                 const int* __restrict__ ptr,
                                                 const int* __restrict__ esrc,
                                                 const float* __restrict__ enorm,
                                                 const float* __restrict__ b2,
                                                 ushort* __restrict__ xbf, int N) {
    int lane16 = threadIdx.x & 15;
    int node = blockIdx.x * 16 + (threadIdx.x >> 4);
    if (node >= N) return;
    float dd = 1.0f / (1.0f + (float)cnt[node]);
    float acc[8];
    {
        const short8 v = *reinterpret_cast<const short8*>(&h2[(size_t)node * 128 + lane16 * 8]);
#pragma unroll
        for (int i = 0; i < 8; ++i) acc[i] = bf2f((ushort)v[i]) * dd;
    }
    int i = ptr[node], end = ptr[node + 1];
    for (; i < end; ++i) {
        const int s = esrc[i];
        const float nm = enorm[i];
        const short8 v = *reinterpret_cast<const short8*>(&h2[(size_t)s * 128 + lane16 * 8]);
#pragma unroll
        for (int q = 0; q < 8; ++q) acc[q] += bf2f((ushort)v[q]) * nm;
    }
    short8 r;
#pragma unroll
    for (int q = 0; q < 8; ++q) {
        r[q] = (short)f2bf(fmaxf(acc[q] + b2[lane16 * 8 + q], 0.f));
    }
    *reinterpret_cast<short8*>(&xbf[(size_t)node * 128 + lane16 * 8]) = r;
}

// ---------------- uv GEMM via MFMA: uv[N,256] = xbf[N,128] @ Wuv^T (bf16 out) ----------------
// Block: 512 thr = 8 waves, 64 nodes. Wave: 16 nodes x 128-col half, K=128.
__global__ __launch_bounds__(512) void k_gemm_uv(const ushort* __restrict__ xbf,
                                                 const ushort* __restrict__ Wuv,
                                                 ushort* __restrict__ uv, int N) {
    __shared__ ushort ldsW[256 * 128];   // 64 KB, XOR-swizzled (256B rows)
    const int tid = threadIdx.x;
    const int wave = tid >> 6, lane = tid & 63;
    const int m = lane & 15, kb = lane >> 4;
    const int ng = wave >> 1;            // node group 0..3
    const int ch = wave & 1;             // col half 0..1
    const int n0 = blockIdx.x * 64 + ng * 16;

    const int node_a = min(n0 + m, N - 1);
    short8 a[4];
#pragma unroll
    for (int kk = 0; kk < 4; ++kk) {
        a[kk] = *reinterpret_cast<const short8*>(&xbf[(size_t)node_a * 128 + kk * 32 + kb * 8]);
    }

    {
        char* lb = reinterpret_cast<char*>(ldsW);
        const short8* wg = reinterpret_cast<const short8*>(Wuv);
#pragma unroll
        for (int i = 0; i < 8; ++i) {
            const int g = i * 512 + tid;
            const int bo = g * 16;
            const int swz = bo ^ (((bo >> 8) & 7) << 4);
            *reinterpret_cast<short8*>(lb + swz) = wg[g];
        }
    }
    __syncthreads();

    f32x4 acc[8];
#pragma unroll
    for (int t = 0; t < 8; ++t) acc[t] = (f32x4){0.f, 0.f, 0.f, 0.f};

    const char* lbr = reinterpret_cast<const char*>(ldsW);
    const int mswz = (m & 7) << 4;
#pragma unroll
    for (int kk = 0; kk < 4; ++kk) {
#pragma unroll
        for (int t = 0; t < 8; ++t) {
            const int bo = (ch * 128 + t * 16 + m) * 256 + kk * 64 + kb * 16;
            const short8 b = *reinterpret_cast<const short8*>(lbr + (bo ^ mswz));
            acc[t] = __builtin_amdgcn_mfma_f32_16x16x32_bf16(a[kk], b, acc[t], 0, 0, 0);
        }
    }

    // C layout: col = ch*128 + t*16 + m, row(node) = kb*4 + r
#pragma unroll
    for (int r = 0; r < 4; ++r) {
        const int node = n0 + kb * 4 + r;
        if (node < N) {
#pragma unroll
            for (int t = 0; t < 8; ++t) {
                uv[(size_t)node * 256 + ch * 128 + t * 16 + m] = f2bf(acc[t][r]);
            }
        }
    }
}

// ---------------- edge kernel: probs from u[src]+v[dst], plus bbox/bidx outputs ----------------
// 16 lanes per edge; grid-stride.
__global__ __launch_bounds__(256) void k_edge_lite(const ushort* __restrict__ uv,
                                                   const float* __restrict__ lin1b,
                                                   const float* __restrict__ linfW,
                                                   const float* __restrict__ linfb,
                                                   const float* __restrict__ bboxes,
                                                   const int* __restrict__ bidx,
                                                   const int* __restrict__ row,
                                                   const int* __restrict__ col,
                                                   float* __restrict__ out_probs,
                                                   float* __restrict__ out_bbox,
                                                   float* __restrict__ out_bidx,
                                                   int E) {
    const int lane16 = threadIdx.x & 15;
    const int slot = threadIdx.x >> 4;       // 16 edges per 256-thr block iteration
    float b8[8], wd8[8];
#pragma unroll
    for (int j = 0; j < 8; ++j) {
        const int c = lane16 * 8 + j;
        b8[j] = lin1b[c];
        wd8[j] = linfW[c * 2] - linfW[c * 2 + 1];
    }
    const float bias_d = linfb[0] - linfb[1];
    const int step = gridDim.x * 16;
    for (int e = blockIdx.x * 16 + slot; e < E; e += step) {
        const int s = row[e], d = col[e];
        const short8 u8 = *reinterpret_cast<const short8*>(&uv[(size_t)s * 256 + lane16 * 8]);
        const short8 v8 = *reinterpret_cast<const short8*>(&uv[(size_t)d * 256 + 128 + lane16 * 8]);
        float p = 0.f;
#pragma unroll
        for (int j = 0; j < 8; ++j) {
            const float hv = fmaxf(bf2f((ushort)u8[j]) + bf2f((ushort)v8[j]) + b8[j], 0.f);
            p = fmaf(hv, wd8[j], p);
        }
#pragma unroll
        for (int t = 1; t < 16; t <<= 1) p += __shfl_xor(p, t);
        if (lane16 < 8) {
            const int node = (lane16 < 4) ? s : d;
            out_bbox[(size_t)e * 8 + lane16] = bboxes[(size_t)node * 4 + (lane16 & 3)];
        } else if (lane16 < 10) {
            const int node = (lane16 == 8) ? s : d;
            out_bidx[(size_t)e * 2 + (lane16 - 8)] = (float)bidx[node];
        } else if (lane16 == 10) {
            const float dd = p + bias_d;                 // z0 - z1
            const float ad = fabsf(dd);
            const float t = -log1pf(expf(-ad));
            const float2 pr = (dd >= 0.f) ? make_float2(t, t - ad) : make_float2(t - ad, t);
            *reinterpret_cast<float2*>(&out_probs[(size_t)e * 2]) = pr;
        }
    }
}

extern "C" void kernel_launch(void* const* d_in, const int* in_sizes, int n_in,
                              void* d_out, int out_size, void* d_ws, size_t ws_size,
                              hipStream_t stream) {
    const float* feat   = (const float*)d_in[0];
    const float* bboxes = (const float*)d_in[1];
    const int*   bidx   = (const int*)d_in[2];
    const int*   eidx   = (const int*)d_in[3];
    const float* W1     = (const float*)d_in[4];
    const float* b1     = (const float*)d_in[5];
    const float* W2     = (const float*)d_in[6];
    const float* b2     = (const float*)d_in[7];
    const float* lin1W  = (const float*)d_in[8];
    const float* lin1b  = (const float*)d_in[9];
    const float* linfW  = (const float*)d_in[10];
    const float* linfb  = (const float*)d_in[11];

    const int N = in_sizes[0] / 8;
    const int E = in_sizes[3] / 2;
    const int* row = eidx;        // sources
    const int* col = eidx + E;    // targets

    size_t Np = ((size_t)N + 255) & ~255ull;
    size_t Ep = ((size_t)E + 255) & ~255ull;
    size_t A8 = (((size_t)N * 8) + 255) & ~255ull;
    int*    cnt    = (int*)d_ws;                 // Np
    int*    cursor = cnt + Np;                   // Np (zeroed with cnt)
    int*    ptr    = cursor + Np;                // Np+256
    int*    esrc   = ptr + Np + 256;             // Ep
    float*  enorm  = (float*)(esrc + Ep);        // Ep
    float*  aggF   = enorm + Ep;                 // A8 f32
    ushort* x1     = (ushort*)(aggF + A8);       // N*128 bf16 (re-used as xbf)
    ushort* h2     = x1 + (size_t)N * 128;       // N*128 bf16
    ushort* uvbuf  = h2 + (size_t)N * 128;       // N*256 bf16
    ushort* Wuv    = uvbuf + (size_t)N * 256;    // 256*128 bf16
    ushort* W2t    = Wuv + 256 * 128;            // 128*128 bf16
    ushort* xbf    = x1;                         // alias: x1 dead after k_gemm2

    float* out       = (float*)d_out;
    float* out_probs = out;                   // E*2
    float* out_bbox  = out + (size_t)E * 2;   // E*8
    float* out_bidx  = out + (size_t)E * 10;  // E*2

    const int total = N * 128;
    const int B = 256;

    // CSR build + weight prep
    hipMemsetAsync(cnt, 0, 2 * Np * sizeof(int), stream);   // cnt + cursor
    k_hist<<<(E + B - 1) / B, B, 0, stream>>>(col, cnt, E);
    k_scan<<<1, 1024, 0, stream>>>(cnt, ptr, N);
    k_fill<<<(E + B - 1) / B, B, 0, stream>>>(row, col, cnt, ptr, cursor, esrc, enorm, E);
    k_prepWuv<<<(256 * 128 + B - 1) / B, B, 0, stream>>>(lin1W, Wuv);
    k_prepW2<<<(128 * 128 + B - 1) / B, B, 0, stream>>>(W2, W2t);

    // layer 1 (aggregate-first on [N,8], then tiny GEMM)
    k_agg8<<<(N + 31) / 32, B, 0, stream>>>(feat, cnt, ptr, esrc, enorm, aggF, N);
    k_gemm1<<<(total + B - 1) / B, B, 0, stream>>>(aggF, W1, b1, x1, total);

    // layer 2 (MFMA GEMM, then 16-lane gather; xbf aliases x1)
    k_gemm2<<<(N + 63) / 64, B, 0, stream>>>(x1, W2t, h2, N);
    k_gather2<<<(N + 15) / 16, B, 0, stream>>>(h2, cnt, ptr, esrc, enorm, b2, xbf, N);

    // per-node edge-MLP projections: uv = xbf @ [W_top|W_bot]
    k_gemm_uv<<<(N + 63) / 64, 512, 0, stream>>>(xbf, Wuv, uvbuf, N);

    // per-edge epilogue + outputs
    k_edge_lite<<<2048, B, 0, stream>>>(uvbuf, lin1b, linfW, linfb,
                                        bboxes, bidx, row, col,
                                        out_probs, out_bbox, out_bidx, E);
}

// Round 11
// 268.593 us; speedup vs baseline: 1.5048x; 1.2469x over previous
//
#include <hip/hip_runtime.h>
#include <hip/hip_bf16.h>
#include <math.h>

// N=50000 nodes, E=800000 edges, D=128, F_IN=8, C=2
// Output float32: [probs E*2 | bbox_pairs E*8 | bbox_index_pairs E*2]

typedef __attribute__((ext_vector_type(8))) short short8;
typedef __attribute__((ext_vector_type(4))) float f32x4;

__device__ inline ushort f2bf(float f) {
    union { __hip_bfloat16 h; ushort u; } cv;
    cv.h = __float2bfloat16(f);
    return cv.u;
}
__device__ inline float bf2f(ushort u) {
    union { float f; uint u; } c;
    c.u = ((uint)u) << 16;
    return c.f;
}

// ---------------- CSR build ----------------
__global__ void k_hist(const int* __restrict__ col, int* __restrict__ cnt, int E) {
    int e = blockIdx.x * blockDim.x + threadIdx.x;
    if (e < E) atomicAdd(&cnt[col[e]], 1);
}

// chunk sums: block b reduces cnt[b*2048 .. b*2048+2047] -> bsum[b]
__global__ __launch_bounds__(1024) void k_bsum(const int* __restrict__ cnt,
                                               int* __restrict__ bsum, int N) {
    __shared__ int ts[1024];
    const int b = blockIdx.x, t = threadIdx.x;
    const int i0 = b * 2048 + 2 * t;
    int a0 = (i0 < N) ? cnt[i0] : 0;
    int a1 = (i0 + 1 < N) ? cnt[i0 + 1] : 0;
    ts[t] = a0 + a1;
    __syncthreads();
#pragma unroll
    for (int off = 512; off > 0; off >>= 1) {
        if (t < off) ts[t] += ts[t + off];
        __syncthreads();
    }
    if (t == 0) bsum[b] = ts[0];
}

// per-chunk exclusive scan + global offset: writes final ptr; ptr[N] = E
__global__ __launch_bounds__(1024) void k_scanw(const int* __restrict__ cnt,
                                                const int* __restrict__ bsum,
                                                int* __restrict__ ptr, int N, int E) {
    __shared__ int ts[1024];
    const int b = blockIdx.x, t = threadIdx.x;
    int boff = 0;
    for (int i = 0; i < b; ++i) boff += bsum[i];
    const int i0 = b * 2048 + 2 * t;
    const int a0 = (i0 < N) ? cnt[i0] : 0;
    const int a1 = (i0 + 1 < N) ? cnt[i0 + 1] : 0;
    const int s = a0 + a1;
    ts[t] = s;
    __syncthreads();
    for (int off = 1; off < 1024; off <<= 1) {
        int v = (t >= off) ? ts[t - off] : 0;
        __syncthreads();
        ts[t] += v;
        __syncthreads();
    }
    const int excl = boff + ts[t] - s;
    if (i0 < N) ptr[i0] = excl;
    if (i0 + 1 < N) ptr[i0 + 1] = excl + a0;
    if (b == 0 && t == 0) ptr[N] = E;
}

__global__ void k_fill(const int* __restrict__ row, const int* __restrict__ col,
                       const int* __restrict__ cnt, const int* __restrict__ ptr,
                       int* __restrict__ cursor, int* __restrict__ esrc,
                       float* __restrict__ enorm, int E) {
    int e = blockIdx.x * blockDim.x + threadIdx.x;
    if (e >= E) return;
    int r = row[e], c = col[e];
    float dr = rsqrtf(1.0f + (float)cnt[r]);
    float dc = rsqrtf(1.0f + (float)cnt[c]);
    int p = ptr[c] + atomicAdd(&cursor[c], 1);
    esrc[p] = r;
    enorm[p] = dr * dc;
}

// ---------------- weight prep ----------------
// Wuv[c][k], c<256, k<128:  c<128: W[k][c] (u = x*W_top) ; c>=128: W[128+k][c-128] (v = x*W_bot)
__global__ void k_prepWuv(const float* __restrict__ W, ushort* __restrict__ Wuv) {
    int tid = blockIdx.x * blockDim.x + threadIdx.x;
    if (tid >= 256 * 128) return;
    int c = tid >> 7, k = tid & 127;
    int krow = k + ((c >> 7) << 7);
    Wuv[tid] = f2bf(W[krow * 128 + (c & 127)]);
}
// W2t[n][k] = bf16(W2[k][n])
__global__ void k_prepW2(const float* __restrict__ W, ushort* __restrict__ Wt) {
    int tid = blockIdx.x * blockDim.x + threadIdx.x;
    if (tid >= 128 * 128) return;
    int n = tid >> 7, k = tid & 127;
    Wt[tid] = f2bf(W[k * 128 + n]);
}

// ---------------- layer-1 aggregate on raw features [N,8] ----------------
__global__ __launch_bounds__(256) void k_agg8(const float* __restrict__ feat,
                                              const int* __restrict__ cnt,
                                              const int* __restrict__ ptr,
                                              const int* __restrict__ esrc,
                                              const float* __restrict__ enorm,
                                              float* __restrict__ aggF, int N) {
    int lane8 = threadIdx.x & 7;
    int node = blockIdx.x * 32 + (threadIdx.x >> 3);
    if (node >= N) return;
    float dd = 1.0f / (1.0f + (float)cnt[node]);
    float acc = feat[(size_t)node * 8 + lane8] * dd;
    int i = ptr[node], end = ptr[node + 1];
    for (; i < end; ++i) {
        acc += feat[(size_t)esrc[i] * 8 + lane8] * enorm[i];
    }
    aggF[(size_t)node * 8 + lane8] = acc;
}

// ---------------- layer-1 GEMM: x1 = bf16(relu(aggF[N,8] @ W1 + b1)) ----------------
__global__ __launch_bounds__(256) void k_gemm1(const float* __restrict__ aggF,
                                               const float* __restrict__ W1,
                                               const float* __restrict__ b1,
                                               ushort* __restrict__ x1, int total) {
    int tid = blockIdx.x * blockDim.x + threadIdx.x;
    if (tid >= total) return;
    int n = tid >> 7, j = tid & 127;
    float acc = b1[j];
#pragma unroll
    for (int k = 0; k < 8; ++k) acc += aggF[(size_t)n * 8 + k] * W1[k * 128 + j];
    x1[tid] = f2bf(fmaxf(acc, 0.f));
}

// ---------------- layer-2 GEMM via MFMA: h2 = x1[N,128] @ W2 (bf16 out) ----------------
// Block: 256 thr = 4 waves, 64 nodes. Wave: 16 nodes x 128 cols, K=128.  (proven R5 shape)
__global__ __launch_bounds__(256) void k_gemm2(const ushort* __restrict__ x1,
                                               const ushort* __restrict__ W2t,
                                               ushort* __restrict__ h2, int N) {
    __shared__ ushort ldsW[128 * 128];   // 32 KB, XOR-swizzled (256B rows)
    const int tid = threadIdx.x;
    const int wave = tid >> 6, lane = tid & 63;
    const int m = lane & 15, kb = lane >> 4;
    const int n0 = blockIdx.x * 64;

    const int node_a = min(n0 + wave * 16 + m, N - 1);
    short8 a[4];
#pragma unroll
    for (int kk = 0; kk < 4; ++kk) {
        a[kk] = *reinterpret_cast<const short8*>(&x1[(size_t)node_a * 128 + kk * 32 + kb * 8]);
    }

    {
        char* lb = reinterpret_cast<char*>(ldsW);
        const short8* wg = reinterpret_cast<const short8*>(W2t);
#pragma unroll
        for (int i = 0; i < 8; ++i) {
            const int g = i * 256 + tid;
            const int bo = g * 16;
            const int swz = bo ^ (((bo >> 8) & 7) << 4);
            *reinterpret_cast<short8*>(lb + swz) = wg[g];
        }
    }
    __syncthreads();

    f32x4 acc[8];
#pragma unroll
    for (int t = 0; t < 8; ++t) acc[t] = (f32x4){0.f, 0.f, 0.f, 0.f};

    const char* lbr = reinterpret_cast<const char*>(ldsW);
    const int mswz = (m & 7) << 4;
#pragma unroll
    for (int kk = 0; kk < 4; ++kk) {
#pragma unroll
        for (int t = 0; t < 8; ++t) {
            const int bo = (t * 16 + m) * 256 + kk * 64 + kb * 16;
            const short8 b = *reinterpret_cast<const short8*>(lbr + (bo ^ mswz));
            acc[t] = __builtin_amdgcn_mfma_f32_16x16x32_bf16(a[kk], b, acc[t], 0, 0, 0);
        }
    }

#pragma unroll
    for (int r = 0; r < 4; ++r) {
        const int node = n0 + wave * 16 + kb * 4 + r;
        if (node < N) {
#pragma unroll
            for (int t = 0; t < 8; ++t) {
                h2[(size_t)node * 128 + t * 16 + m] = f2bf(acc[t][r]);
            }
        }
    }
}

// ---------------- layer-2 aggregate (16 lanes/node, short8/lane; proven R5 shape) ----------------
__global__ __launch_bounds__(256) void k_gather2(const ushort* __restrict__ h2,
                                                 const int* __restrict__ cnt,
                                                 const int* __restrict__ ptr,
                                                 const int* __restrict__ esrc,
                                                 const float* __restrict__ enorm,
                                                 const float* __restrict__ b2,
                                                 ushort* __restrict__ xbf, int N) {
    int lane16 = threadIdx.x & 15;
    int node = blockIdx.x * 16 + (threadIdx.x >> 4);
    if (node >= N) return;
    float dd = 1.0f / (1.0f + (float)cnt[node]);
    float acc[8];
    {
        const short8 v = *reinterpret_cast<const short8*>(&h2[(size_t)node * 128 + lane16 * 8]);
#pragma unroll
        for (int i = 0; i < 8; ++i) acc[i] = bf2f((ushort)v[i]) * dd;
    }
    int i = ptr[node], end = ptr[node + 1];
    for (; i < end; ++i) {
        const int s = esrc[i];
        const float nm = enorm[i];
        const short8 v = *reinterpret_cast<const short8*>(&h2[(size_t)s * 128 + lane16 * 8]);
#pragma unroll
        for (int q = 0; q < 8; ++q) acc[q] += bf2f((ushort)v[q]) * nm;
    }
    short8 r;
#pragma unroll
    for (int q = 0; q < 8; ++q) {
        r[q] = (short)f2bf(fmaxf(acc[q] + b2[lane16 * 8 + q], 0.f));
    }
    *reinterpret_cast<short8*>(&xbf[(size_t)node * 128 + lane16 * 8]) = r;
}

// ---------------- uv GEMM via MFMA: uv[N,256] = xbf[N,128] @ Wuv^T (bf16 out) ----------------
// Block: 512 thr = 8 waves, 64 nodes. Wave: 16 nodes x 128-col half, K=128.
__global__ __launch_bounds__(512) void k_gemm_uv(const ushort* __restrict__ xbf,
                                                 const ushort* __restrict__ Wuv,
                                                 ushort* __restrict__ uv, int N) {
    __shared__ ushort ldsW[256 * 128];   // 64 KB, XOR-swizzled (256B rows)
    const int tid = threadIdx.x;
    const int wave = tid >> 6, lane = tid & 63;
    const int m = lane & 15, kb = lane >> 4;
    const int ng = wave >> 1;            // node group 0..3
    const int ch = wave & 1;             // col half 0..1
    const int n0 = blockIdx.x * 64 + ng * 16;

    const int node_a = min(n0 + m, N - 1);
    short8 a[4];
#pragma unroll
    for (int kk = 0; kk < 4; ++kk) {
        a[kk] = *reinterpret_cast<const short8*>(&xbf[(size_t)node_a * 128 + kk * 32 + kb * 8]);
    }

    {
        char* lb = reinterpret_cast<char*>(ldsW);
        const short8* wg = reinterpret_cast<const short8*>(Wuv);
#pragma unroll
        for (int i = 0; i < 8; ++i) {
            const int g = i * 512 + tid;
            const int bo = g * 16;
            const int swz = bo ^ (((bo >> 8) & 7) << 4);
            *reinterpret_cast<short8*>(lb + swz) = wg[g];
        }
    }
    __syncthreads();

    f32x4 acc[8];
#pragma unroll
    for (int t = 0; t < 8; ++t) acc[t] = (f32x4){0.f, 0.f, 0.f, 0.f};

    const char* lbr = reinterpret_cast<const char*>(ldsW);
    const int mswz = (m & 7) << 4;
#pragma unroll
    for (int kk = 0; kk < 4; ++kk) {
#pragma unroll
        for (int t = 0; t < 8; ++t) {
            const int bo = (ch * 128 + t * 16 + m) * 256 + kk * 64 + kb * 16;
            const short8 b = *reinterpret_cast<const short8*>(lbr + (bo ^ mswz));
            acc[t] = __builtin_amdgcn_mfma_f32_16x16x32_bf16(a[kk], b, acc[t], 0, 0, 0);
        }
    }

    // C layout: col = ch*128 + t*16 + m, row(node) = kb*4 + r
#pragma unroll
    for (int r = 0; r < 4; ++r) {
        const int node = n0 + kb * 4 + r;
        if (node < N) {
#pragma unroll
            for (int t = 0; t < 8; ++t) {
                uv[(size_t)node * 256 + ch * 128 + t * 16 + m] = f2bf(acc[t][r]);
            }
        }
    }
}

// ---------------- edge kernel: probs from u[src]+v[dst], plus bbox/bidx outputs ----------------
// 16 lanes per edge; grid-stride.
__global__ __launch_bounds__(256) void k_edge_lite(const ushort* __restrict__ uv,
                                                   const float* __restrict__ lin1b,
                                                   const float* __restrict__ linfW,
                                                   const float* __restrict__ linfb,
                                                   const float* __restrict__ bboxes,
                                                   const int* __restrict__ bidx,
                                                   const int* __restrict__ row,
                                                   const int* __restrict__ col,
                                                   float* __restrict__ out_probs,
                                                   float* __restrict__ out_bbox,
                                                   float* __restrict__ out_bidx,
                                                   int E) {
    const int lane16 = threadIdx.x & 15;
    const int slot = threadIdx.x >> 4;       // 16 edges per 256-thr block iteration
    float b8[8], wd8[8];
#pragma unroll
    for (int j = 0; j < 8; ++j) {
        const int c = lane16 * 8 + j;
        b8[j] = lin1b[c];
        wd8[j] = linfW[c * 2] - linfW[c * 2 + 1];
    }
    const float bias_d = linfb[0] - linfb[1];
    const int step = gridDim.x * 16;
    for (int e = blockIdx.x * 16 + slot; e < E; e += step) {
        const int s = row[e], d = col[e];
        const short8 u8 = *reinterpret_cast<const short8*>(&uv[(size_t)s * 256 + lane16 * 8]);
        const short8 v8 = *reinterpret_cast<const short8*>(&uv[(size_t)d * 256 + 128 + lane16 * 8]);
        float p = 0.f;
#pragma unroll
        for (int j = 0; j < 8; ++j) {
            const float hv = fmaxf(bf2f((ushort)u8[j]) + bf2f((ushort)v8[j]) + b8[j], 0.f);
            p = fmaf(hv, wd8[j], p);
        }
#pragma unroll
        for (int t = 1; t < 16; t <<= 1) p += __shfl_xor(p, t);
        if (lane16 < 8) {
            const int node = (lane16 < 4) ? s : d;
            out_bbox[(size_t)e * 8 + lane16] = bboxes[(size_t)node * 4 + (lane16 & 3)];
        } else if (lane16 < 10) {
            const int node = (lane16 == 8) ? s : d;
            out_bidx[(size_t)e * 2 + (lane16 - 8)] = (float)bidx[node];
        } else if (lane16 == 10) {
            const float dd = p + bias_d;                 // z0 - z1
            const float ad = fabsf(dd);
            const float t = -log1pf(expf(-ad));
            const float2 pr = (dd >= 0.f) ? make_float2(t, t - ad) : make_float2(t - ad, t);
            *reinterpret_cast<float2*>(&out_probs[(size_t)e * 2]) = pr;
        }
    }
}

extern "C" void kernel_launch(void* const* d_in, const int* in_sizes, int n_in,
                              void* d_out, int out_size, void* d_ws, size_t ws_size,
                              hipStream_t stream) {
    const float* feat   = (const float*)d_in[0];
    const float* bboxes = (const float*)d_in[1];
    const int*   bidx   = (const int*)d_in[2];
    const int*   eidx   = (const int*)d_in[3];
    const float* W1     = (const float*)d_in[4];
    const float* b1     = (const float*)d_in[5];
    const float* W2     = (const float*)d_in[6];
    const float* b2     = (const float*)d_in[7];
    const float* lin1W  = (const float*)d_in[8];
    const float* lin1b  = (const float*)d_in[9];
    const float* linfW  = (const float*)d_in[10];
    const float* linfb  = (const float*)d_in[11];

    const int N = in_sizes[0] / 8;
    const int E = in_sizes[3] / 2;
    const int* row = eidx;        // sources
    const int* col = eidx + E;    // targets

    size_t Np = ((size_t)N + 255) & ~255ull;
    size_t Ep = ((size_t)E + 255) & ~255ull;
    size_t A8 = (((size_t)N * 8) + 255) & ~255ull;
    int*    cnt    = (int*)d_ws;                 // Np
    int*    cursor = cnt + Np;                   // Np (zeroed with cnt)
    int*    ptr    = cursor + Np;                // Np+256
    int*    bsum   = ptr + Np + 256;             // 256
    int*    esrc   = bsum + 256;                 // Ep
    float*  enorm  = (float*)(esrc + Ep);        // Ep
    float*  aggF   = enorm + Ep;                 // A8 f32
    ushort* x1     = (ushort*)(aggF + A8);       // N*128 bf16 (re-used as xbf)
    ushort* h2     = x1 + (size_t)N * 128;       // N*128 bf16
    ushort* uvbuf  = h2 + (size_t)N * 128;       // N*256 bf16
    ushort* Wuv    = uvbuf + (size_t)N * 256;    // 256*128 bf16
    ushort* W2t    = Wuv + 256 * 128;            // 128*128 bf16
    ushort* xbf    = x1;                         // alias: x1 dead after k_gemm2

    float* out       = (float*)d_out;
    float* out_probs = out;                   // E*2
    float* out_bbox  = out + (size_t)E * 2;   // E*8
    float* out_bidx  = out + (size_t)E * 10;  // E*2

    const int total = N * 128;
    const int B = 256;
    const int nchunk = (N + 2047) / 2048;

    // CSR build + weight prep
    hipMemsetAsync(cnt, 0, 2 * Np * sizeof(int), stream);   // cnt + cursor
    k_hist<<<(E + B - 1) / B, B, 0, stream>>>(col, cnt, E);
    k_bsum<<<nchunk, 1024, 0, stream>>>(cnt, bsum, N);
    k_scanw<<<nchunk, 1024, 0, stream>>>(cnt, bsum, ptr, N, E);
    k_fill<<<(E + B - 1) / B, B, 0, stream>>>(row, col, cnt, ptr, cursor, esrc, enorm, E);
    k_prepWuv<<<(256 * 128 + B - 1) / B, B, 0, stream>>>(lin1W, Wuv);
    k_prepW2<<<(128 * 128 + B - 1) / B, B, 0, stream>>>(W2, W2t);

    // layer 1 (aggregate-first on [N,8], then tiny GEMM)
    k_agg8<<<(N + 31) / 32, B, 0, stream>>>(feat, cnt, ptr, esrc, enorm, aggF, N);
    k_gemm1<<<(total + B - 1) / B, B, 0, stream>>>(aggF, W1, b1, x1, total);

    // layer 2 (MFMA GEMM, then 16-lane gather; xbf aliases x1)
    k_gemm2<<<(N + 63) / 64, B, 0, stream>>>(x1, W2t, h2, N);
    k_gather2<<<(N + 15) / 16, B, 0, stream>>>(h2, cnt, ptr, esrc, enorm, b2, xbf, N);

    // per-node edge-MLP projections: uv = xbf @ [W_top|W_bot]
    k_gemm_uv<<<(N + 63) / 64, 512, 0, stream>>>(xbf, Wuv, uvbuf, N);

    // per-edge epilogue + outputs
    k_edge_lite<<<2048, B, 0, stream>>>(uvbuf, lin1b, linfW, linfb,
                                        bboxes, bidx, row, col,
                                        out_probs, out_bbox, out_bidx, E);
}

// Round 12
// 265.604 us; speedup vs baseline: 1.5218x; 1.0113x over previous
//
#include <hip/hip_runtime.h>
#include <hip/hip_bf16.h>
#include <math.h>

// N=50000 nodes, E=800000 edges, D=128, F_IN=8, C=2
// Output float32: [probs E*2 | bbox_pairs E*8 | bbox_index_pairs E*2]

typedef __attribute__((ext_vector_type(8))) short short8;
typedef __attribute__((ext_vector_type(4))) float f32x4;
typedef _Float16 half2v __attribute__((ext_vector_type(2)));

__device__ inline ushort f2bf(float f) {
    union { __hip_bfloat16 h; ushort u; } cv;
    cv.h = __float2bfloat16(f);
    return cv.u;
}
__device__ inline float bf2f(ushort u) {
    union { float f; uint u; } c;
    c.u = ((uint)u) << 16;
    return c.f;
}
__device__ inline ushort f2h(float f) {
    union { _Float16 h; ushort u; } c;
    c.h = (_Float16)f;
    return c.u;
}

// ---------------- CSR build ----------------
__global__ void k_hist(const int* __restrict__ col, int* __restrict__ cnt, int E) {
    int e = blockIdx.x * blockDim.x + threadIdx.x;
    if (e < E) atomicAdd(&cnt[col[e]], 1);
}

// chunk sums: block b reduces cnt[b*2048 .. b*2048+2047] -> bsum[b]
__global__ __launch_bounds__(1024) void k_bsum(const int* __restrict__ cnt,
                                               int* __restrict__ bsum, int N) {
    __shared__ int ts[1024];
    const int b = blockIdx.x, t = threadIdx.x;
    const int i0 = b * 2048 + 2 * t;
    int a0 = (i0 < N) ? cnt[i0] : 0;
    int a1 = (i0 + 1 < N) ? cnt[i0 + 1] : 0;
    ts[t] = a0 + a1;
    __syncthreads();
#pragma unroll
    for (int off = 512; off > 0; off >>= 1) {
        if (t < off) ts[t] += ts[t + off];
        __syncthreads();
    }
    if (t == 0) bsum[b] = ts[0];
}

// per-chunk exclusive scan + global offset: writes final ptr; ptr[N] = E
__global__ __launch_bounds__(1024) void k_scanw(const int* __restrict__ cnt,
                                                const int* __restrict__ bsum,
                                                int* __restrict__ ptr, int N, int E) {
    __shared__ int ts[1024];
    const int b = blockIdx.x, t = threadIdx.x;
    int boff = 0;
    for (int i = 0; i < b; ++i) boff += bsum[i];
    const int i0 = b * 2048 + 2 * t;
    const int a0 = (i0 < N) ? cnt[i0] : 0;
    const int a1 = (i0 + 1 < N) ? cnt[i0 + 1] : 0;
    const int s = a0 + a1;
    ts[t] = s;
    __syncthreads();
    for (int off = 1; off < 1024; off <<= 1) {
        int v = (t >= off) ? ts[t - off] : 0;
        __syncthreads();
        ts[t] += v;
        __syncthreads();
    }
    const int excl = boff + ts[t] - s;
    if (i0 < N) ptr[i0] = excl;
    if (i0 + 1 < N) ptr[i0 + 1] = excl + a0;
    if (b == 0 && t == 0) ptr[N] = E;
}

// fill CSR: packed (src, norm-bits) in one 8B store
__global__ void k_fill(const int* __restrict__ row, const int* __restrict__ col,
                       const int* __restrict__ cnt, const int* __restrict__ ptr,
                       int* __restrict__ cursor, int2* __restrict__ eadj, int E) {
    int e = blockIdx.x * blockDim.x + threadIdx.x;
    if (e >= E) return;
    int r = row[e], c = col[e];
    float dr = rsqrtf(1.0f + (float)cnt[r]);
    float dc = rsqrtf(1.0f + (float)cnt[c]);
    int p = ptr[c] + atomicAdd(&cursor[c], 1);
    eadj[p] = make_int2(r, __float_as_int(dr * dc));
}

// ---------------- weight prep ----------------
// Wuv[c][k], c<256, k<128:  c<128: W[k][c] (u = x*W_top) ; c>=128: W[128+k][c-128] (v = x*W_bot)
__global__ void k_prepWuv(const float* __restrict__ W, ushort* __restrict__ Wuv) {
    int tid = blockIdx.x * blockDim.x + threadIdx.x;
    if (tid >= 256 * 128) return;
    int c = tid >> 7, k = tid & 127;
    int krow = k + ((c >> 7) << 7);
    Wuv[tid] = f2bf(W[krow * 128 + (c & 127)]);
}
// W2t[n][k] = bf16(W2[k][n])
__global__ void k_prepW2(const float* __restrict__ W, ushort* __restrict__ Wt) {
    int tid = blockIdx.x * blockDim.x + threadIdx.x;
    if (tid >= 128 * 128) return;
    int n = tid >> 7, k = tid & 127;
    Wt[tid] = f2bf(W[k * 128 + n]);
}

// ---------------- layer-1 aggregate on raw features [N,8] ----------------
__global__ __launch_bounds__(256) void k_agg8(const float* __restrict__ feat,
                                              const int* __restrict__ cnt,
                                              const int* __restrict__ ptr,
                                              const int2* __restrict__ eadj,
                                              float* __restrict__ aggF, int N) {
    int lane8 = threadIdx.x & 7;
    int node = blockIdx.x * 32 + (threadIdx.x >> 3);
    if (node >= N) return;
    float dd = 1.0f / (1.0f + (float)cnt[node]);
    float acc = feat[(size_t)node * 8 + lane8] * dd;
    int i = ptr[node], end = ptr[node + 1];
    for (; i < end; ++i) {
        const int2 a = eadj[i];
        acc += feat[(size_t)a.x * 8 + lane8] * __int_as_float(a.y);
    }
    aggF[(size_t)node * 8 + lane8] = acc;
}

// ---------------- layer-1 GEMM: x1 = bf16(relu(aggF[N,8] @ W1 + b1)) ----------------
__global__ __launch_bounds__(256) void k_gemm1(const float* __restrict__ aggF,
                                               const float* __restrict__ W1,
                                               const float* __restrict__ b1,
                                               ushort* __restrict__ x1, int total) {
    int tid = blockIdx.x * blockDim.x + threadIdx.x;
    if (tid >= total) return;
    int n = tid >> 7, j = tid & 127;
    float acc = b1[j];
#pragma unroll
    for (int k = 0; k < 8; ++k) acc += aggF[(size_t)n * 8 + k] * W1[k * 128 + j];
    x1[tid] = f2bf(fmaxf(acc, 0.f));
}

// ---------------- layer-2 GEMM via MFMA: h2 = x1[N,128] @ W2 (bf16 out) ----------------
// Block: 256 thr = 4 waves, 64 nodes. Wave: 16 nodes x 128 cols, K=128.  (proven R5 shape)
__global__ __launch_bounds__(256) void k_gemm2(const ushort* __restrict__ x1,
                                               const ushort* __restrict__ W2t,
                                               ushort* __restrict__ h2, int N) {
    __shared__ ushort ldsW[128 * 128];   // 32 KB, XOR-swizzled (256B rows)
    const int tid = threadIdx.x;
    const int wave = tid >> 6, lane = tid & 63;
    const int m = lane & 15, kb = lane >> 4;
    const int n0 = blockIdx.x * 64;

    const int node_a = min(n0 + wave * 16 + m, N - 1);
    short8 a[4];
#pragma unroll
    for (int kk = 0; kk < 4; ++kk) {
        a[kk] = *reinterpret_cast<const short8*>(&x1[(size_t)node_a * 128 + kk * 32 + kb * 8]);
    }

    {
        char* lb = reinterpret_cast<char*>(ldsW);
        const short8* wg = reinterpret_cast<const short8*>(W2t);
#pragma unroll
        for (int i = 0; i < 8; ++i) {
            const int g = i * 256 + tid;
            const int bo = g * 16;
            const int swz = bo ^ (((bo >> 8) & 7) << 4);
            *reinterpret_cast<short8*>(lb + swz) = wg[g];
        }
    }
    __syncthreads();

    f32x4 acc[8];
#pragma unroll
    for (int t = 0; t < 8; ++t) acc[t] = (f32x4){0.f, 0.f, 0.f, 0.f};

    const char* lbr = reinterpret_cast<const char*>(ldsW);
    const int mswz = (m & 7) << 4;
#pragma unroll
    for (int kk = 0; kk < 4; ++kk) {
#pragma unroll
        for (int t = 0; t < 8; ++t) {
            const int bo = (t * 16 + m) * 256 + kk * 64 + kb * 16;
            const short8 b = *reinterpret_cast<const short8*>(lbr + (bo ^ mswz));
            acc[t] = __builtin_amdgcn_mfma_f32_16x16x32_bf16(a[kk], b, acc[t], 0, 0, 0);
        }
    }

#pragma unroll
    for (int r = 0; r < 4; ++r) {
        const int node = n0 + wave * 16 + kb * 4 + r;
        if (node < N) {
#pragma unroll
            for (int t = 0; t < 8; ++t) {
                h2[(size_t)node * 128 + t * 16 + m] = f2bf(acc[t][r]);
            }
        }
    }
}

// ---------------- layer-2 aggregate (16 lanes/node, short8/lane; proven R5 shape) ----------------
__global__ __launch_bounds__(256) void k_gather2(const ushort* __restrict__ h2,
                                                 const int* __restrict__ cnt,
                                                 const int* __restrict__ ptr,
                                                 const int2* __restrict__ eadj,
                                                 const float* __restrict__ b2,
                                                 ushort* __restrict__ xbf, int N) {
    int lane16 = threadIdx.x & 15;
    int node = blockIdx.x * 16 + (threadIdx.x >> 4);
    if (node >= N) return;
    float dd = 1.0f / (1.0f + (float)cnt[node]);
    float acc[8];
    {
        const short8 v = *reinterpret_cast<const short8*>(&h2[(size_t)node * 128 + lane16 * 8]);
#pragma unroll
        for (int i = 0; i < 8; ++i) acc[i] = bf2f((ushort)v[i]) * dd;
    }
    int i = ptr[node], end = ptr[node + 1];
    for (; i < end; ++i) {
        const int2 aa = eadj[i];
        const int s = aa.x;
        const float nm = __int_as_float(aa.y);
        const short8 v = *reinterpret_cast<const short8*>(&h2[(size_t)s * 128 + lane16 * 8]);
#pragma unroll
        for (int q = 0; q < 8; ++q) acc[q] += bf2f((ushort)v[q]) * nm;
    }
    short8 r;
#pragma unroll
    for (int q = 0; q < 8; ++q) {
        r[q] = (short)f2bf(fmaxf(acc[q] + b2[lane16 * 8 + q], 0.f));
    }
    *reinterpret_cast<short8*>(&xbf[(size_t)node * 128 + lane16 * 8]) = r;
}

// ---------------- uv GEMM via MFMA: uv[N,256] = fp16(xbf[N,128] @ Wuv^T); bias folded into u ----------------
// Block: 512 thr = 8 waves, 64 nodes. Wave: 16 nodes x 128-col half, K=128.
__global__ __launch_bounds__(512) void k_gemm_uv(const ushort* __restrict__ xbf,
                                                 const ushort* __restrict__ Wuv,
                                                 const float* __restrict__ lin1b,
                                                 ushort* __restrict__ uv, int N) {
    __shared__ ushort ldsW[256 * 128];   // 64 KB, XOR-swizzled (256B rows)
    const int tid = threadIdx.x;
    const int wave = tid >> 6, lane = tid & 63;
    const int m = lane & 15, kb = lane >> 4;
    const int ng = wave >> 1;            // node group 0..3
    const int ch = wave & 1;             // col half 0..1 (0 = u, 1 = v)
    const int n0 = blockIdx.x * 64 + ng * 16;

    const int node_a = min(n0 + m, N - 1);
    short8 a[4];
#pragma unroll
    for (int kk = 0; kk < 4; ++kk) {
        a[kk] = *reinterpret_cast<const short8*>(&xbf[(size_t)node_a * 128 + kk * 32 + kb * 8]);
    }

    {
        char* lb = reinterpret_cast<char*>(ldsW);
        const short8* wg = reinterpret_cast<const short8*>(Wuv);
#pragma unroll
        for (int i = 0; i < 8; ++i) {
            const int g = i * 512 + tid;
            const int bo = g * 16;
            const int swz = bo ^ (((bo >> 8) & 7) << 4);
            *reinterpret_cast<short8*>(lb + swz) = wg[g];
        }
    }
    __syncthreads();

    f32x4 acc[8];
#pragma unroll
    for (int t = 0; t < 8; ++t) acc[t] = (f32x4){0.f, 0.f, 0.f, 0.f};

    const char* lbr = reinterpret_cast<const char*>(ldsW);
    const int mswz = (m & 7) << 4;
#pragma unroll
    for (int kk = 0; kk < 4; ++kk) {
#pragma unroll
        for (int t = 0; t < 8; ++t) {
            const int bo = (ch * 128 + t * 16 + m) * 256 + kk * 64 + kb * 16;
            const short8 b = *reinterpret_cast<const short8*>(lbr + (bo ^ mswz));
            acc[t] = __builtin_amdgcn_mfma_f32_16x16x32_bf16(a[kk], b, acc[t], 0, 0, 0);
        }
    }

    // C layout: col = ch*128 + t*16 + m, row(node) = kb*4 + r. u-half gets +lin1b.
#pragma unroll
    for (int r = 0; r < 4; ++r) {
        const int node = n0 + kb * 4 + r;
        if (node < N) {
#pragma unroll
            for (int t = 0; t < 8; ++t) {
                const int c = t * 16 + m;
                float av = acc[t][r];
                if (ch == 0) av += lin1b[c];
                uv[(size_t)node * 256 + ch * 128 + c] = f2h(av);
            }
        }
    }
}

// ---------------- edge kernel: probs from fp16 u'[src]+v[dst] (packed VOP3P), bbox/bidx ----------------
// 16 lanes per edge; grid-stride.
__global__ __launch_bounds__(256) void k_edge_lite(const ushort* __restrict__ uv,
                                                   const float* __restrict__ linfW,
                                                   const float* __restrict__ linfb,
                                                   const float* __restrict__ bboxes,
                                                   const int* __restrict__ bidx,
                                                   const int* __restrict__ row,
                                                   const int* __restrict__ col,
                                                   float* __restrict__ out_probs,
                                                   float* __restrict__ out_bbox,
                                                   float* __restrict__ out_bidx,
                                                   int E) {
    const int lane16 = threadIdx.x & 15;
    const int slot = threadIdx.x >> 4;       // 16 edges per 256-thr block iteration
    half2v wd2[4];
#pragma unroll
    for (int j = 0; j < 4; ++j) {
        const int c = lane16 * 8 + 2 * j;
        wd2[j][0] = (_Float16)(linfW[c * 2] - linfW[c * 2 + 1]);
        wd2[j][1] = (_Float16)(linfW[(c + 1) * 2] - linfW[(c + 1) * 2 + 1]);
    }
    const float bias_d = linfb[0] - linfb[1];
    const half2v zero2 = {(_Float16)0, (_Float16)0};
    const int step = gridDim.x * 16;
    union HU { uint u; half2v h; };
    for (int e = blockIdx.x * 16 + slot; e < E; e += step) {
        const int s = row[e], d = col[e];
        const uint4 ua = *reinterpret_cast<const uint4*>(&uv[(size_t)s * 256 + lane16 * 8]);
        const uint4 va = *reinterpret_cast<const uint4*>(&uv[(size_t)d * 256 + 128 + lane16 * 8]);
        half2v acc2 = zero2;
        {
            HU cu, cv;
            cu.u = ua.x; cv.u = va.x;
            acc2 += __builtin_elementwise_max(cu.h + cv.h, zero2) * wd2[0];
            cu.u = ua.y; cv.u = va.y;
            acc2 += __builtin_elementwise_max(cu.h + cv.h, zero2) * wd2[1];
            cu.u = ua.z; cv.u = va.z;
            acc2 += __builtin_elementwise_max(cu.h + cv.h, zero2) * wd2[2];
            cu.u = ua.w; cv.u = va.w;
            acc2 += __builtin_elementwise_max(cu.h + cv.h, zero2) * wd2[3];
        }
        float p = (float)acc2[0] + (float)acc2[1];
#pragma unroll
        for (int t = 1; t < 16; t <<= 1) p += __shfl_xor(p, t);
        if (lane16 < 8) {
            const int node = (lane16 < 4) ? s : d;
            out_bbox[(size_t)e * 8 + lane16] = bboxes[(size_t)node * 4 + (lane16 & 3)];
        } else if (lane16 < 10) {
            const int node = (lane16 == 8) ? s : d;
            out_bidx[(size_t)e * 2 + (lane16 - 8)] = (float)bidx[node];
        } else if (lane16 == 10) {
            const float dd = p + bias_d;                 // z0 - z1
            const float ad = fabsf(dd);
            const float t = -log1pf(expf(-ad));
            const float2 pr = (dd >= 0.f) ? make_float2(t, t - ad) : make_float2(t - ad, t);
            *reinterpret_cast<float2*>(&out_probs[(size_t)e * 2]) = pr;
        }
    }
}

extern "C" void kernel_launch(void* const* d_in, const int* in_sizes, int n_in,
                              void* d_out, int out_size, void* d_ws, size_t ws_size,
                              hipStream_t stream) {
    const float* feat   = (const float*)d_in[0];
    const float* bboxes = (const float*)d_in[1];
    const int*   bidx   = (const int*)d_in[2];
    const int*   eidx   = (const int*)d_in[3];
    const float* W1     = (const float*)d_in[4];
    const float* b1     = (const float*)d_in[5];
    const float* W2     = (const float*)d_in[6];
    const float* b2     = (const float*)d_in[7];
    const float* lin1W  = (const float*)d_in[8];
    const float* lin1b  = (const float*)d_in[9];
    const float* linfW  = (const float*)d_in[10];
    const float* linfb  = (const float*)d_in[11];

    const int N = in_sizes[0] / 8;
    const int E = in_sizes[3] / 2;
    const int* row = eidx;        // sources
    const int* col = eidx + E;    // targets

    size_t Np = ((size_t)N + 255) & ~255ull;
    size_t Ep = ((size_t)E + 255) & ~255ull;
    size_t A8 = (((size_t)N * 8) + 255) & ~255ull;
    int*    cnt    = (int*)d_ws;                 // Np
    int*    cursor = cnt + Np;                   // Np (zeroed with cnt)
    int*    ptr    = cursor + Np;                // Np+256
    int*    bsum   = ptr + Np + 256;             // 256
    int2*   eadj   = (int2*)(bsum + 256);        // Ep int2 (src, norm-bits)
    float*  aggF   = (float*)(eadj + Ep);        // A8 f32
    ushort* x1     = (ushort*)(aggF + A8);       // N*128 bf16 (re-used as xbf)
    ushort* h2     = x1 + (size_t)N * 128;       // N*128 bf16
    ushort* uvbuf  = h2 + (size_t)N * 128;       // N*256 fp16
    ushort* Wuv    = uvbuf + (size_t)N * 256;    // 256*128 bf16
    ushort* W2t    = Wuv + 256 * 128;            // 128*128 bf16
    ushort* xbf    = x1;                         // alias: x1 dead after k_gemm2

    float* out       = (float*)d_out;
    float* out_probs = out;                   // E*2
    float* out_bbox  = out + (size_t)E * 2;   // E*8
    float* out_bidx  = out + (size_t)E * 10;  // E*2

    const int total = N * 128;
    const int B = 256;
    const int nchunk = (N + 2047) / 2048;

    // CSR build + weight prep
    hipMemsetAsync(cnt, 0, 2 * Np * sizeof(int), stream);   // cnt + cursor
    k_hist<<<(E + B - 1) / B, B, 0, stream>>>(col, cnt, E);
    k_bsum<<<nchunk, 1024, 0, stream>>>(cnt, bsum, N);
    k_scanw<<<nchunk, 1024, 0, stream>>>(cnt, bsum, ptr, N, E);
    k_fill<<<(E + B - 1) / B, B, 0, stream>>>(row, col, cnt, ptr, cursor, eadj, E);
    k_prepWuv<<<(256 * 128 + B - 1) / B, B, 0, stream>>>(lin1W, Wuv);
    k_prepW2<<<(128 * 128 + B - 1) / B, B, 0, stream>>>(W2, W2t);

    // layer 1 (aggregate-first on [N,8], then tiny GEMM)
    k_agg8<<<(N + 31) / 32, B, 0, stream>>>(feat, cnt, ptr, eadj, aggF, N);
    k_gemm1<<<(total + B - 1) / B, B, 0, stream>>>(aggF, W1, b1, x1, total);

    // layer 2 (MFMA GEMM, then 16-lane gather; xbf aliases x1)
    k_gemm2<<<(N + 63) / 64, B, 0, stream>>>(x1, W2t, h2, N);
    k_gather2<<<(N + 15) / 16, B, 0, stream>>>(h2, cnt, ptr, eadj, b2, xbf, N);

    // per-node edge-MLP projections: uv = fp16(xbf @ [W_top|W_bot]), bias folded into u
    k_gemm_uv<<<(N + 63) / 64, 512, 0, stream>>>(xbf, Wuv, lin1b, uvbuf, N);

    // per-edge epilogue + outputs
    k_edge_lite<<<2048, B, 0, stream>>>(uvbuf, linfW, linfb,
                                        bboxes, bidx, row, col,
                                        out_probs, out_bbox, out_bidx, E);
}

// Round 13
// 261.246 us; speedup vs baseline: 1.5472x; 1.0167x over previous
//
#include <hip/hip_runtime.h>
#include <hip/hip_bf16.h>
#include <math.h>

// N=50000 nodes, E=800000 edges, D=128, F_IN=8, C=2
// Output float32: [probs E*2 | bbox_pairs E*8 | bbox_index_pairs E*2]

typedef __attribute__((ext_vector_type(8))) short short8;
typedef __attribute__((ext_vector_type(4))) float f32x4;
typedef __attribute__((ext_vector_type(2))) float fv2;

__device__ inline ushort f2bf(float f) {
    union { __hip_bfloat16 h; ushort u; } cv;
    cv.h = __float2bfloat16(f);
    return cv.u;
}
__device__ inline float bf2f(ushort u) {
    union { float f; uint u; } c;
    c.u = ((uint)u) << 16;
    return c.f;
}
__device__ inline uchar f2fp8(float f) {
    // OCP e4m3 via HW pack (low byte of packed pair)
    uint p = __builtin_amdgcn_cvt_pk_fp8_f32(f, f, 0u, false);
    return (uchar)(p & 0xffu);
}

// ---------------- CSR build ----------------
__global__ void k_hist(const int* __restrict__ col, int* __restrict__ cnt, int E) {
    int e = blockIdx.x * blockDim.x + threadIdx.x;
    if (e < E) atomicAdd(&cnt[col[e]], 1);
}

// chunk sums: block b reduces cnt[b*2048 .. b*2048+2047] -> bsum[b]
__global__ __launch_bounds__(1024) void k_bsum(const int* __restrict__ cnt,
                                               int* __restrict__ bsum, int N) {
    __shared__ int ts[1024];
    const int b = blockIdx.x, t = threadIdx.x;
    const int i0 = b * 2048 + 2 * t;
    int a0 = (i0 < N) ? cnt[i0] : 0;
    int a1 = (i0 + 1 < N) ? cnt[i0 + 1] : 0;
    ts[t] = a0 + a1;
    __syncthreads();
#pragma unroll
    for (int off = 512; off > 0; off >>= 1) {
        if (t < off) ts[t] += ts[t + off];
        __syncthreads();
    }
    if (t == 0) bsum[b] = ts[0];
}

// per-chunk exclusive scan + global offset: writes final ptr; ptr[N] = E
__global__ __launch_bounds__(1024) void k_scanw(const int* __restrict__ cnt,
                                                const int* __restrict__ bsum,
                                                int* __restrict__ ptr, int N, int E) {
    __shared__ int ts[1024];
    const int b = blockIdx.x, t = threadIdx.x;
    int boff = 0;
    for (int i = 0; i < b; ++i) boff += bsum[i];
    const int i0 = b * 2048 + 2 * t;
    const int a0 = (i0 < N) ? cnt[i0] : 0;
    const int a1 = (i0 + 1 < N) ? cnt[i0 + 1] : 0;
    const int s = a0 + a1;
    ts[t] = s;
    __syncthreads();
    for (int off = 1; off < 1024; off <<= 1) {
        int v = (t >= off) ? ts[t - off] : 0;
        __syncthreads();
        ts[t] += v;
        __syncthreads();
    }
    const int excl = boff + ts[t] - s;
    if (i0 < N) ptr[i0] = excl;
    if (i0 + 1 < N) ptr[i0 + 1] = excl + a0;
    if (b == 0 && t == 0) ptr[N] = E;
}

// fill CSR: packed (src, norm-bits) in one 8B store
__global__ void k_fill(const int* __restrict__ row, const int* __restrict__ col,
                       const int* __restrict__ cnt, const int* __restrict__ ptr,
                       int* __restrict__ cursor, int2* __restrict__ eadj, int E) {
    int e = blockIdx.x * blockDim.x + threadIdx.x;
    if (e >= E) return;
    int r = row[e], c = col[e];
    float dr = rsqrtf(1.0f + (float)cnt[r]);
    float dc = rsqrtf(1.0f + (float)cnt[c]);
    int p = ptr[c] + atomicAdd(&cursor[c], 1);
    eadj[p] = make_int2(r, __float_as_int(dr * dc));
}

// ---------------- weight prep ----------------
// Wuv[c][k], c<256, k<128:  c<128: W[k][c] (u = x*W_top) ; c>=128: W[128+k][c-128] (v = x*W_bot)
__global__ void k_prepWuv(const float* __restrict__ W, ushort* __restrict__ Wuv) {
    int tid = blockIdx.x * blockDim.x + threadIdx.x;
    if (tid >= 256 * 128) return;
    int c = tid >> 7, k = tid & 127;
    int krow = k + ((c >> 7) << 7);
    Wuv[tid] = f2bf(W[krow * 128 + (c & 127)]);
}
// W2t[n][k] = bf16(W2[k][n])
__global__ void k_prepW2(const float* __restrict__ W, ushort* __restrict__ Wt) {
    int tid = blockIdx.x * blockDim.x + threadIdx.x;
    if (tid >= 128 * 128) return;
    int n = tid >> 7, k = tid & 127;
    Wt[tid] = f2bf(W[k * 128 + n]);
}

// ---------------- layer-1 aggregate on raw features [N,8] ----------------
__global__ __launch_bounds__(256) void k_agg8(const float* __restrict__ feat,
                                              const int* __restrict__ cnt,
                                              const int* __restrict__ ptr,
                                              const int2* __restrict__ eadj,
                                              float* __restrict__ aggF, int N) {
    int lane8 = threadIdx.x & 7;
    int node = blockIdx.x * 32 + (threadIdx.x >> 3);
    if (node >= N) return;
    float dd = 1.0f / (1.0f + (float)cnt[node]);
    float acc = feat[(size_t)node * 8 + lane8] * dd;
    int i = ptr[node], end = ptr[node + 1];
    for (; i < end; ++i) {
        const int2 a = eadj[i];
        acc += feat[(size_t)a.x * 8 + lane8] * __int_as_float(a.y);
    }
    aggF[(size_t)node * 8 + lane8] = acc;
}

// ---------------- layer-1 GEMM: x1 = bf16(relu(aggF[N,8] @ W1 + b1)) ----------------
__global__ __launch_bounds__(256) void k_gemm1(const float* __restrict__ aggF,
                                               const float* __restrict__ W1,
                                               const float* __restrict__ b1,
                                               ushort* __restrict__ x1, int total) {
    int tid = blockIdx.x * blockDim.x + threadIdx.x;
    if (tid >= total) return;
    int n = tid >> 7, j = tid & 127;
    float acc = b1[j];
#pragma unroll
    for (int k = 0; k < 8; ++k) acc += aggF[(size_t)n * 8 + k] * W1[k * 128 + j];
    x1[tid] = f2bf(fmaxf(acc, 0.f));
}

// ---------------- layer-2 GEMM via MFMA: h2 = x1[N,128] @ W2 (bf16 out) ----------------
// Block: 256 thr = 4 waves, 64 nodes. Wave: 16 nodes x 128 cols, K=128.  (proven R5 shape)
__global__ __launch_bounds__(256) void k_gemm2(const ushort* __restrict__ x1,
                                               const ushort* __restrict__ W2t,
                                               ushort* __restrict__ h2, int N) {
    __shared__ ushort ldsW[128 * 128];   // 32 KB, XOR-swizzled (256B rows)
    const int tid = threadIdx.x;
    const int wave = tid >> 6, lane = tid & 63;
    const int m = lane & 15, kb = lane >> 4;
    const int n0 = blockIdx.x * 64;

    const int node_a = min(n0 + wave * 16 + m, N - 1);
    short8 a[4];
#pragma unroll
    for (int kk = 0; kk < 4; ++kk) {
        a[kk] = *reinterpret_cast<const short8*>(&x1[(size_t)node_a * 128 + kk * 32 + kb * 8]);
    }

    {
        char* lb = reinterpret_cast<char*>(ldsW);
        const short8* wg = reinterpret_cast<const short8*>(W2t);
#pragma unroll
        for (int i = 0; i < 8; ++i) {
            const int g = i * 256 + tid;
            const int bo = g * 16;
            const int swz = bo ^ (((bo >> 8) & 7) << 4);
            *reinterpret_cast<short8*>(lb + swz) = wg[g];
        }
    }
    __syncthreads();

    f32x4 acc[8];
#pragma unroll
    for (int t = 0; t < 8; ++t) acc[t] = (f32x4){0.f, 0.f, 0.f, 0.f};

    const char* lbr = reinterpret_cast<const char*>(ldsW);
    const int mswz = (m & 7) << 4;
#pragma unroll
    for (int kk = 0; kk < 4; ++kk) {
#pragma unroll
        for (int t = 0; t < 8; ++t) {
            const int bo = (t * 16 + m) * 256 + kk * 64 + kb * 16;
            const short8 b = *reinterpret_cast<const short8*>(lbr + (bo ^ mswz));
            acc[t] = __builtin_amdgcn_mfma_f32_16x16x32_bf16(a[kk], b, acc[t], 0, 0, 0);
        }
    }

#pragma unroll
    for (int r = 0; r < 4; ++r) {
        const int node = n0 + wave * 16 + kb * 4 + r;
        if (node < N) {
#pragma unroll
            for (int t = 0; t < 8; ++t) {
                h2[(size_t)node * 128 + t * 16 + m] = f2bf(acc[t][r]);
            }
        }
    }
}

// ---------------- layer-2 aggregate (16 lanes/node, short8/lane; proven R5 shape) ----------------
__global__ __launch_bounds__(256) void k_gather2(const ushort* __restrict__ h2,
                                                 const int* __restrict__ cnt,
                                                 const int* __restrict__ ptr,
                                                 const int2* __restrict__ eadj,
                                                 const float* __restrict__ b2,
                                                 ushort* __restrict__ xbf, int N) {
    int lane16 = threadIdx.x & 15;
    int node = blockIdx.x * 16 + (threadIdx.x >> 4);
    if (node >= N) return;
    float dd = 1.0f / (1.0f + (float)cnt[node]);
    float acc[8];
    {
        const short8 v = *reinterpret_cast<const short8*>(&h2[(size_t)node * 128 + lane16 * 8]);
#pragma unroll
        for (int i = 0; i < 8; ++i) acc[i] = bf2f((ushort)v[i]) * dd;
    }
    int i = ptr[node], end = ptr[node + 1];
    for (; i < end; ++i) {
        const int2 aa = eadj[i];
        const int s = aa.x;
        const float nm = __int_as_float(aa.y);
        const short8 v = *reinterpret_cast<const short8*>(&h2[(size_t)s * 128 + lane16 * 8]);
#pragma unroll
        for (int q = 0; q < 8; ++q) acc[q] += bf2f((ushort)v[q]) * nm;
    }
    short8 r;
#pragma unroll
    for (int q = 0; q < 8; ++q) {
        r[q] = (short)f2bf(fmaxf(acc[q] + b2[lane16 * 8 + q], 0.f));
    }
    *reinterpret_cast<short8*>(&xbf[(size_t)node * 128 + lane16 * 8]) = r;
}

// ---------------- uv GEMM via MFMA: uv[N,256] = fp8(xbf[N,128] @ Wuv^T); bias folded into u ----------------
// Block: 512 thr = 8 waves, 64 nodes. Wave: 16 nodes x 128-col half, K=128.
__global__ __launch_bounds__(512) void k_gemm_uv(const ushort* __restrict__ xbf,
                                                 const ushort* __restrict__ Wuv,
                                                 const float* __restrict__ lin1b,
                                                 uchar* __restrict__ uv, int N) {
    __shared__ ushort ldsW[256 * 128];   // 64 KB, XOR-swizzled (256B rows)
    const int tid = threadIdx.x;
    const int wave = tid >> 6, lane = tid & 63;
    const int m = lane & 15, kb = lane >> 4;
    const int ng = wave >> 1;            // node group 0..3
    const int ch = wave & 1;             // col half 0..1 (0 = u, 1 = v)
    const int n0 = blockIdx.x * 64 + ng * 16;

    const int node_a = min(n0 + m, N - 1);
    short8 a[4];
#pragma unroll
    for (int kk = 0; kk < 4; ++kk) {
        a[kk] = *reinterpret_cast<const short8*>(&xbf[(size_t)node_a * 128 + kk * 32 + kb * 8]);
    }

    {
        char* lb = reinterpret_cast<char*>(ldsW);
        const short8* wg = reinterpret_cast<const short8*>(Wuv);
#pragma unroll
        for (int i = 0; i < 8; ++i) {
            const int g = i * 512 + tid;
            const int bo = g * 16;
            const int swz = bo ^ (((bo >> 8) & 7) << 4);
            *reinterpret_cast<short8*>(lb + swz) = wg[g];
        }
    }
    __syncthreads();

    f32x4 acc[8];
#pragma unroll
    for (int t = 0; t < 8; ++t) acc[t] = (f32x4){0.f, 0.f, 0.f, 0.f};

    const char* lbr = reinterpret_cast<const char*>(ldsW);
    const int mswz = (m & 7) << 4;
#pragma unroll
    for (int kk = 0; kk < 4; ++kk) {
#pragma unroll
        for (int t = 0; t < 8; ++t) {
            const int bo = (ch * 128 + t * 16 + m) * 256 + kk * 64 + kb * 16;
            const short8 b = *reinterpret_cast<const short8*>(lbr + (bo ^ mswz));
            acc[t] = __builtin_amdgcn_mfma_f32_16x16x32_bf16(a[kk], b, acc[t], 0, 0, 0);
        }
    }

    // C layout: col = ch*128 + t*16 + m, row(node) = kb*4 + r. u-half gets +lin1b.
#pragma unroll
    for (int r = 0; r < 4; ++r) {
        const int node = n0 + kb * 4 + r;
        if (node < N) {
#pragma unroll
            for (int t = 0; t < 8; ++t) {
                const int c = t * 16 + m;
                float av = acc[t][r];
                if (ch == 0) av += lin1b[c];
                uv[(size_t)node * 256 + ch * 128 + c] = f2fp8(av);
            }
        }
    }
}

// ---------------- edge kernel: probs from fp8 u'[src]+v[dst], bbox/bidx ----------------
// 16 lanes per edge; grid-stride.
__global__ __launch_bounds__(256) void k_edge_lite(const uchar* __restrict__ uv,
                                                   const float* __restrict__ linfW,
                                                   const float* __restrict__ linfb,
                                                   const float* __restrict__ bboxes,
                                                   const int* __restrict__ bidx,
                                                   const int* __restrict__ row,
                                                   const int* __restrict__ col,
                                                   float* __restrict__ out_probs,
                                                   float* __restrict__ out_bbox,
                                                   float* __restrict__ out_bidx,
                                                   int E) {
    const int lane16 = threadIdx.x & 15;
    const int slot = threadIdx.x >> 4;       // 16 edges per 256-thr block iteration
    float wd[8];
#pragma unroll
    for (int j = 0; j < 8; ++j) {
        const int c = lane16 * 8 + j;
        wd[j] = linfW[c * 2] - linfW[c * 2 + 1];
    }
    const float bias_d = linfb[0] - linfb[1];
    const int step = gridDim.x * 16;
    for (int e = blockIdx.x * 16 + slot; e < E; e += step) {
        const int s = row[e], d = col[e];
        const uint2 ua = *reinterpret_cast<const uint2*>(&uv[(size_t)s * 256 + lane16 * 8]);
        const uint2 va = *reinterpret_cast<const uint2*>(&uv[(size_t)d * 256 + 128 + lane16 * 8]);
        const fv2 u01 = __builtin_amdgcn_cvt_pk_f32_fp8(ua.x, false);
        const fv2 u23 = __builtin_amdgcn_cvt_pk_f32_fp8(ua.x, true);
        const fv2 u45 = __builtin_amdgcn_cvt_pk_f32_fp8(ua.y, false);
        const fv2 u67 = __builtin_amdgcn_cvt_pk_f32_fp8(ua.y, true);
        const fv2 v01 = __builtin_amdgcn_cvt_pk_f32_fp8(va.x, false);
        const fv2 v23 = __builtin_amdgcn_cvt_pk_f32_fp8(va.x, true);
        const fv2 v45 = __builtin_amdgcn_cvt_pk_f32_fp8(va.y, false);
        const fv2 v67 = __builtin_amdgcn_cvt_pk_f32_fp8(va.y, true);
        float p;
        {
            float h0 = fmaxf(u01[0] + v01[0], 0.f);
            float h1 = fmaxf(u01[1] + v01[1], 0.f);
            float h2 = fmaxf(u23[0] + v23[0], 0.f);
            float h3 = fmaxf(u23[1] + v23[1], 0.f);
            float h4 = fmaxf(u45[0] + v45[0], 0.f);
            float h5 = fmaxf(u45[1] + v45[1], 0.f);
            float h6 = fmaxf(u67[0] + v67[0], 0.f);
            float h7 = fmaxf(u67[1] + v67[1], 0.f);
            p = h0 * wd[0];
            p = fmaf(h1, wd[1], p);
            p = fmaf(h2, wd[2], p);
            p = fmaf(h3, wd[3], p);
            p = fmaf(h4, wd[4], p);
            p = fmaf(h5, wd[5], p);
            p = fmaf(h6, wd[6], p);
            p = fmaf(h7, wd[7], p);
        }
#pragma unroll
        for (int t = 1; t < 16; t <<= 1) p += __shfl_xor(p, t);
        if (lane16 < 8) {
            const int node = (lane16 < 4) ? s : d;
            out_bbox[(size_t)e * 8 + lane16] = bboxes[(size_t)node * 4 + (lane16 & 3)];
        } else if (lane16 < 10) {
            const int node = (lane16 == 8) ? s : d;
            out_bidx[(size_t)e * 2 + (lane16 - 8)] = (float)bidx[node];
        } else if (lane16 == 10) {
            const float dd = p + bias_d;                 // z0 - z1
            const float ad = fabsf(dd);
            const float t = -log1pf(expf(-ad));
            const float2 pr = (dd >= 0.f) ? make_float2(t, t - ad) : make_float2(t - ad, t);
            *reinterpret_cast<float2*>(&out_probs[(size_t)e * 2]) = pr;
        }
    }
}

extern "C" void kernel_launch(void* const* d_in, const int* in_sizes, int n_in,
                              void* d_out, int out_size, void* d_ws, size_t ws_size,
                              hipStream_t stream) {
    const float* feat   = (const float*)d_in[0];
    const float* bboxes = (const float*)d_in[1];
    const int*   bidx   = (const int*)d_in[2];
    const int*   eidx   = (const int*)d_in[3];
    const float* W1     = (const float*)d_in[4];
    const float* b1     = (const float*)d_in[5];
    const float* W2     = (const float*)d_in[6];
    const float* b2     = (const float*)d_in[7];
    const float* lin1W  = (const float*)d_in[8];
    const float* lin1b  = (const float*)d_in[9];
    const float* linfW  = (const float*)d_in[10];
    const float* linfb  = (const float*)d_in[11];

    const int N = in_sizes[0] / 8;
    const int E = in_sizes[3] / 2;
    const int* row = eidx;        // sources
    const int* col = eidx + E;    // targets

    size_t Np = ((size_t)N + 255) & ~255ull;
    size_t Ep = ((size_t)E + 255) & ~255ull;
    size_t A8 = (((size_t)N * 8) + 255) & ~255ull;
    int*    cnt    = (int*)d_ws;                 // Np
    int*    cursor = cnt + Np;                   // Np (zeroed with cnt)
    int*    ptr    = cursor + Np;                // Np+256
    int*    bsum   = ptr + Np + 256;             // 256
    int2*   eadj   = (int2*)(bsum + 256);        // Ep int2 (src, norm-bits)
    float*  aggF   = (float*)(eadj + Ep);        // A8 f32
    ushort* x1     = (ushort*)(aggF + A8);       // N*128 bf16 (re-used as xbf)
    ushort* h2     = x1 + (size_t)N * 128;       // N*128 bf16
    uchar*  uvbuf  = (uchar*)(h2 + (size_t)N * 128);   // N*256 fp8
    ushort* Wuv    = (ushort*)(uvbuf + (size_t)N * 256); // 256*128 bf16
    ushort* W2t    = Wuv + 256 * 128;            // 128*128 bf16
    ushort* xbf    = x1;                         // alias: x1 dead after k_gemm2

    float* out       = (float*)d_out;
    float* out_probs = out;                   // E*2
    float* out_bbox  = out + (size_t)E * 2;   // E*8
    float* out_bidx  = out + (size_t)E * 10;  // E*2

    const int total = N * 128;
    const int B = 256;
    const int nchunk = (N + 2047) / 2048;

    // CSR build + weight prep
    hipMemsetAsync(cnt, 0, 2 * Np * sizeof(int), stream);   // cnt + cursor
    k_hist<<<(E + B - 1) / B, B, 0, stream>>>(col, cnt, E);
    k_bsum<<<nchunk, 1024, 0, stream>>>(cnt, bsum, N);
    k_scanw<<<nchunk, 1024, 0, stream>>>(cnt, bsum, ptr, N, E);
    k_fill<<<(E + B - 1) / B, B, 0, stream>>>(row, col, cnt, ptr, cursor, eadj, E);
    k_prepWuv<<<(256 * 128 + B - 1) / B, B, 0, stream>>>(lin1W, Wuv);
    k_prepW2<<<(128 * 128 + B - 1) / B, B, 0, stream>>>(W2, W2t);

    // layer 1 (aggregate-first on [N,8], then tiny GEMM)
    k_agg8<<<(N + 31) / 32, B, 0, stream>>>(feat, cnt, ptr, eadj, aggF, N);
    k_gemm1<<<(total + B - 1) / B, B, 0, stream>>>(aggF, W1, b1, x1, total);

    // layer 2 (MFMA GEMM, then 16-lane gather; xbf aliases x1)
    k_gemm2<<<(N + 63) / 64, B, 0, stream>>>(x1, W2t, h2, N);
    k_gather2<<<(N + 15) / 16, B, 0, stream>>>(h2, cnt, ptr, eadj, b2, xbf, N);

    // per-node edge-MLP projections: uv = fp8(xbf @ [W_top|W_bot]), bias folded into u
    k_gemm_uv<<<(N + 63) / 64, 512, 0, stream>>>(xbf, Wuv, lin1b, uvbuf, N);

    // per-edge epilogue + outputs
    k_edge_lite<<<2048, B, 0, stream>>>(uvbuf, linfW, linfb,
                                        bboxes, bidx, row, col,
                                        out_probs, out_bbox, out_bidx, E);
}

// Round 14
// 248.102 us; speedup vs baseline: 1.6291x; 1.0530x over previous
//
#include <hip/hip_runtime.h>
#include <hip/hip_bf16.h>
#include <math.h>

// N=50000 nodes, E=800000 edges, D=128, F_IN=8, C=2
// Output float32: [probs E*2 | bbox_pairs E*8 | bbox_index_pairs E*2]

typedef __attribute__((ext_vector_type(8))) short short8;
typedef __attribute__((ext_vector_type(4))) float f32x4;
typedef __attribute__((ext_vector_type(2))) float fv2;

__device__ inline ushort f2bf(float f) {
    union { __hip_bfloat16 h; ushort u; } cv;
    cv.h = __float2bfloat16(f);
    return cv.u;
}
__device__ inline float bf2f(ushort u) {
    union { float f; uint u; } c;
    c.u = ((uint)u) << 16;
    return c.f;
}
__device__ inline uchar f2fp8(float f) {
    // OCP e4m3 via HW pack (low byte of packed pair)
    uint p = __builtin_amdgcn_cvt_pk_fp8_f32(f, f, 0u, false);
    return (uchar)(p & 0xffu);
}

// ---------------- CSR build ----------------
__global__ void k_hist(const int* __restrict__ col, int* __restrict__ cnt, int E) {
    int e = blockIdx.x * blockDim.x + threadIdx.x;
    if (e < E) atomicAdd(&cnt[col[e]], 1);
}

// chunk sums: block b reduces cnt[b*2048 .. b*2048+2047] -> bsum[b]
__global__ __launch_bounds__(1024) void k_bsum(const int* __restrict__ cnt,
                                               int* __restrict__ bsum, int N) {
    __shared__ int ts[1024];
    const int b = blockIdx.x, t = threadIdx.x;
    const int i0 = b * 2048 + 2 * t;
    int a0 = (i0 < N) ? cnt[i0] : 0;
    int a1 = (i0 + 1 < N) ? cnt[i0 + 1] : 0;
    ts[t] = a0 + a1;
    __syncthreads();
#pragma unroll
    for (int off = 512; off > 0; off >>= 1) {
        if (t < off) ts[t] += ts[t + off];
        __syncthreads();
    }
    if (t == 0) bsum[b] = ts[0];
}

// per-chunk exclusive scan + global offset: writes final ptr; ptr[N] = E
__global__ __launch_bounds__(1024) void k_scanw(const int* __restrict__ cnt,
                                                const int* __restrict__ bsum,
                                                int* __restrict__ ptr, int N, int E) {
    __shared__ int ts[1024];
    const int b = blockIdx.x, t = threadIdx.x;
    int boff = 0;
    for (int i = 0; i < b; ++i) boff += bsum[i];
    const int i0 = b * 2048 + 2 * t;
    const int a0 = (i0 < N) ? cnt[i0] : 0;
    const int a1 = (i0 + 1 < N) ? cnt[i0 + 1] : 0;
    const int s = a0 + a1;
    ts[t] = s;
    __syncthreads();
    for (int off = 1; off < 1024; off <<= 1) {
        int v = (t >= off) ? ts[t - off] : 0;
        __syncthreads();
        ts[t] += v;
        __syncthreads();
    }
    const int excl = boff + ts[t] - s;
    if (i0 < N) ptr[i0] = excl;
    if (i0 + 1 < N) ptr[i0 + 1] = excl + a0;
    if (b == 0 && t == 0) ptr[N] = E;
}

// fill CSR: packed (src, norm-bits) in one 8B store
__global__ void k_fill(const int* __restrict__ row, const int* __restrict__ col,
                       const int* __restrict__ cnt, const int* __restrict__ ptr,
                       int* __restrict__ cursor, int2* __restrict__ eadj, int E) {
    int e = blockIdx.x * blockDim.x + threadIdx.x;
    if (e >= E) return;
    int r = row[e], c = col[e];
    float dr = rsqrtf(1.0f + (float)cnt[r]);
    float dc = rsqrtf(1.0f + (float)cnt[c]);
    int p = ptr[c] + atomicAdd(&cursor[c], 1);
    eadj[p] = make_int2(r, __float_as_int(dr * dc));
}

// ---------------- weight prep ----------------
// Wuv[c][k], c<256, k<128:  c<128: W[k][c] (u = x*W_top) ; c>=128: W[128+k][c-128] (v = x*W_bot)
__global__ void k_prepWuv(const float* __restrict__ W, ushort* __restrict__ Wuv) {
    int tid = blockIdx.x * blockDim.x + threadIdx.x;
    if (tid >= 256 * 128) return;
    int c = tid >> 7, k = tid & 127;
    int krow = k + ((c >> 7) << 7);
    Wuv[tid] = f2bf(W[krow * 128 + (c & 127)]);
}
// W2t[n][k] = bf16(W2[k][n])
__global__ void k_prepW2(const float* __restrict__ W, ushort* __restrict__ Wt) {
    int tid = blockIdx.x * blockDim.x + threadIdx.x;
    if (tid >= 128 * 128) return;
    int n = tid >> 7, k = tid & 127;
    Wt[tid] = f2bf(W[k * 128 + n]);
}

// ---------------- layer-1 aggregate on raw features [N,8] ----------------
__global__ __launch_bounds__(256) void k_agg8(const float* __restrict__ feat,
                                              const int* __restrict__ cnt,
                                              const int* __restrict__ ptr,
                                              const int2* __restrict__ eadj,
                                              float* __restrict__ aggF, int N) {
    int lane8 = threadIdx.x & 7;
    int node = blockIdx.x * 32 + (threadIdx.x >> 3);
    if (node >= N) return;
    float dd = 1.0f / (1.0f + (float)cnt[node]);
    float acc = feat[(size_t)node * 8 + lane8] * dd;
    int i = ptr[node], end = ptr[node + 1];
    for (; i < end; ++i) {
        const int2 a = eadj[i];
        acc += feat[(size_t)a.x * 8 + lane8] * __int_as_float(a.y);
    }
    aggF[(size_t)node * 8 + lane8] = acc;
}

// ---------------- layer-1 GEMM: x1 = bf16(relu(aggF[N,8] @ W1 + b1)) ----------------
__global__ __launch_bounds__(256) void k_gemm1(const float* __restrict__ aggF,
                                               const float* __restrict__ W1,
                                               const float* __restrict__ b1,
                                               ushort* __restrict__ x1, int total) {
    int tid = blockIdx.x * blockDim.x + threadIdx.x;
    if (tid >= total) return;
    int n = tid >> 7, j = tid & 127;
    float acc = b1[j];
#pragma unroll
    for (int k = 0; k < 8; ++k) acc += aggF[(size_t)n * 8 + k] * W1[k * 128 + j];
    x1[tid] = f2bf(fmaxf(acc, 0.f));
}

// ---------------- layer-2 GEMM via MFMA: h2 = x1[N,128] @ W2 (bf16 out) ----------------
// Block: 256 thr = 4 waves, 64 nodes. Wave: 16 nodes x 128 cols, K=128.  (proven R5 shape)
__global__ __launch_bounds__(256) void k_gemm2(const ushort* __restrict__ x1,
                                               const ushort* __restrict__ W2t,
                                               ushort* __restrict__ h2, int N) {
    __shared__ ushort ldsW[128 * 128];   // 32 KB, XOR-swizzled (256B rows)
    const int tid = threadIdx.x;
    const int wave = tid >> 6, lane = tid & 63;
    const int m = lane & 15, kb = lane >> 4;
    const int n0 = blockIdx.x * 64;

    const int node_a = min(n0 + wave * 16 + m, N - 1);
    short8 a[4];
#pragma unroll
    for (int kk = 0; kk < 4; ++kk) {
        a[kk] = *reinterpret_cast<const short8*>(&x1[(size_t)node_a * 128 + kk * 32 + kb * 8]);
    }

    {
        char* lb = reinterpret_cast<char*>(ldsW);
        const short8* wg = reinterpret_cast<const short8*>(W2t);
#pragma unroll
        for (int i = 0; i < 8; ++i) {
            const int g = i * 256 + tid;
            const int bo = g * 16;
            const int swz = bo ^ (((bo >> 8) & 7) << 4);
            *reinterpret_cast<short8*>(lb + swz) = wg[g];
        }
    }
    __syncthreads();

    f32x4 acc[8];
#pragma unroll
    for (int t = 0; t < 8; ++t) acc[t] = (f32x4){0.f, 0.f, 0.f, 0.f};

    const char* lbr = reinterpret_cast<const char*>(ldsW);
    const int mswz = (m & 7) << 4;
#pragma unroll
    for (int kk = 0; kk < 4; ++kk) {
#pragma unroll
        for (int t = 0; t < 8; ++t) {
            const int bo = (t * 16 + m) * 256 + kk * 64 + kb * 16;
            const short8 b = *reinterpret_cast<const short8*>(lbr + (bo ^ mswz));
            acc[t] = __builtin_amdgcn_mfma_f32_16x16x32_bf16(a[kk], b, acc[t], 0, 0, 0);
        }
    }

#pragma unroll
    for (int r = 0; r < 4; ++r) {
        const int node = n0 + wave * 16 + kb * 4 + r;
        if (node < N) {
#pragma unroll
            for (int t = 0; t < 8; ++t) {
                h2[(size_t)node * 128 + t * 16 + m] = f2bf(acc[t][r]);
            }
        }
    }
}

// ---------------- layer-2 aggregate (16 lanes/node, short8/lane; proven R5 shape) ----------------
__global__ __launch_bounds__(256) void k_gather2(const ushort* __restrict__ h2,
                                                 const int* __restrict__ cnt,
                                                 const int* __restrict__ ptr,
                                                 const int2* __restrict__ eadj,
                                                 const float* __restrict__ b2,
                                                 ushort* __restrict__ xbf, int N) {
    int lane16 = threadIdx.x & 15;
    int node = blockIdx.x * 16 + (threadIdx.x >> 4);
    if (node >= N) return;
    float dd = 1.0f / (1.0f + (float)cnt[node]);
    float acc[8];
    {
        const short8 v = *reinterpret_cast<const short8*>(&h2[(size_t)node * 128 + lane16 * 8]);
#pragma unroll
        for (int i = 0; i < 8; ++i) acc[i] = bf2f((ushort)v[i]) * dd;
    }
    int i = ptr[node], end = ptr[node + 1];
    for (; i < end; ++i) {
        const int2 aa = eadj[i];
        const int s = aa.x;
        const float nm = __int_as_float(aa.y);
        const short8 v = *reinterpret_cast<const short8*>(&h2[(size_t)s * 128 + lane16 * 8]);
#pragma unroll
        for (int q = 0; q < 8; ++q) acc[q] += bf2f((ushort)v[q]) * nm;
    }
    short8 r;
#pragma unroll
    for (int q = 0; q < 8; ++q) {
        r[q] = (short)f2bf(fmaxf(acc[q] + b2[lane16 * 8 + q], 0.f));
    }
    *reinterpret_cast<short8*>(&xbf[(size_t)node * 128 + lane16 * 8]) = r;
}

// ---------------- uv GEMM via MFMA: uv[N,256] = fp8(xbf[N,128] @ Wuv^T); bias folded into u ----------------
// Block: 512 thr = 8 waves, 64 nodes. Wave: 16 nodes x 128-col half, K=128.
__global__ __launch_bounds__(512) void k_gemm_uv(const ushort* __restrict__ xbf,
                                                 const ushort* __restrict__ Wuv,
                                                 const float* __restrict__ lin1b,
                                                 uchar* __restrict__ uv, int N) {
    __shared__ ushort ldsW[256 * 128];   // 64 KB, XOR-swizzled (256B rows)
    const int tid = threadIdx.x;
    const int wave = tid >> 6, lane = tid & 63;
    const int m = lane & 15, kb = lane >> 4;
    const int ng = wave >> 1;            // node group 0..3
    const int ch = wave & 1;             // col half 0..1 (0 = u, 1 = v)
    const int n0 = blockIdx.x * 64 + ng * 16;

    const int node_a = min(n0 + m, N - 1);
    short8 a[4];
#pragma unroll
    for (int kk = 0; kk < 4; ++kk) {
        a[kk] = *reinterpret_cast<const short8*>(&xbf[(size_t)node_a * 128 + kk * 32 + kb * 8]);
    }

    {
        char* lb = reinterpret_cast<char*>(ldsW);
        const short8* wg = reinterpret_cast<const short8*>(Wuv);
#pragma unroll
        for (int i = 0; i < 8; ++i) {
            const int g = i * 512 + tid;
            const int bo = g * 16;
            const int swz = bo ^ (((bo >> 8) & 7) << 4);
            *reinterpret_cast<short8*>(lb + swz) = wg[g];
        }
    }
    __syncthreads();

    f32x4 acc[8];
#pragma unroll
    for (int t = 0; t < 8; ++t) acc[t] = (f32x4){0.f, 0.f, 0.f, 0.f};

    const char* lbr = reinterpret_cast<const char*>(ldsW);
    const int mswz = (m & 7) << 4;
#pragma unroll
    for (int kk = 0; kk < 4; ++kk) {
#pragma unroll
        for (int t = 0; t < 8; ++t) {
            const int bo = (ch * 128 + t * 16 + m) * 256 + kk * 64 + kb * 16;
            const short8 b = *reinterpret_cast<const short8*>(lbr + (bo ^ mswz));
            acc[t] = __builtin_amdgcn_mfma_f32_16x16x32_bf16(a[kk], b, acc[t], 0, 0, 0);
        }
    }

    // C layout: col = ch*128 + t*16 + m, row(node) = kb*4 + r. u-half gets +lin1b.
#pragma unroll
    for (int r = 0; r < 4; ++r) {
        const int node = n0 + kb * 4 + r;
        if (node < N) {
#pragma unroll
            for (int t = 0; t < 8; ++t) {
                const int c = t * 16 + m;
                float av = acc[t][r];
                if (ch == 0) av += lin1b[c];
                uv[(size_t)node * 256 + ch * 128 + c] = f2fp8(av);
            }
        }
    }
}

// ---------------- edge kernel: 8 lanes/edge, uint4 gathers, 2-deep pipeline ----------------
__global__ __launch_bounds__(256) void k_edge_lite(const uchar* __restrict__ uv,
                                                   const float* __restrict__ linfW,
                                                   const float* __restrict__ linfb,
                                                   const float* __restrict__ bboxes,
                                                   const int* __restrict__ bidx,
                                                   const int* __restrict__ row,
                                                   const int* __restrict__ col,
                                                   float* __restrict__ out_probs,
                                                   float* __restrict__ out_bbox,
                                                   float* __restrict__ out_bidx,
                                                   int E) {
    const int lane8 = threadIdx.x & 7;
    const int slot = threadIdx.x >> 3;       // 32 edges per 256-thr block iteration
    int e = blockIdx.x * 32 + slot;
    if (e >= E) return;

    float wd[16];
#pragma unroll
    for (int j = 0; j < 16; ++j) {
        const int c = lane8 * 16 + j;
        wd[j] = linfW[c * 2] - linfW[c * 2 + 1];
    }
    const float bias_d = linfb[0] - linfb[1];
    const int step = gridDim.x * 32;

    // prologue: first edge's loads in flight
    int s = row[e], d = col[e];
    uint4 ua = *reinterpret_cast<const uint4*>(&uv[(size_t)s * 256 + lane8 * 16]);
    uint4 va = *reinterpret_cast<const uint4*>(&uv[(size_t)d * 256 + 128 + lane8 * 16]);

    while (true) {
        // issue next edge's loads before computing current (hide gather latency)
        const int e2 = e + step;
        const bool more = (e2 < E);
        int s2 = 0, d2 = 0;
        uint4 ua2 = ua, va2 = va;
        if (more) {
            s2 = row[e2];
            d2 = col[e2];
            ua2 = *reinterpret_cast<const uint4*>(&uv[(size_t)s2 * 256 + lane8 * 16]);
            va2 = *reinterpret_cast<const uint4*>(&uv[(size_t)d2 * 256 + 128 + lane8 * 16]);
        }

        // compute current edge: 16 channels/lane
        float p = 0.f;
        {
            const uint uw[4] = {ua.x, ua.y, ua.z, ua.w};
            const uint vw[4] = {va.x, va.y, va.z, va.w};
#pragma unroll
            for (int w = 0; w < 4; ++w) {
                const fv2 ul = __builtin_amdgcn_cvt_pk_f32_fp8(uw[w], false);
                const fv2 uh = __builtin_amdgcn_cvt_pk_f32_fp8(uw[w], true);
                const fv2 vl = __builtin_amdgcn_cvt_pk_f32_fp8(vw[w], false);
                const fv2 vh = __builtin_amdgcn_cvt_pk_f32_fp8(vw[w], true);
                p = fmaf(fmaxf(ul[0] + vl[0], 0.f), wd[4 * w + 0], p);
                p = fmaf(fmaxf(ul[1] + vl[1], 0.f), wd[4 * w + 1], p);
                p = fmaf(fmaxf(uh[0] + vh[0], 0.f), wd[4 * w + 2], p);
                p = fmaf(fmaxf(uh[1] + vh[1], 0.f), wd[4 * w + 3], p);
            }
        }
        // butterfly across the 8 lanes of this edge
        p += __shfl_xor(p, 1);
        p += __shfl_xor(p, 2);
        p += __shfl_xor(p, 4);

        // outputs
        out_bbox[(size_t)e * 8 + lane8] = bboxes[(size_t)((lane8 < 4) ? s : d) * 4 + (lane8 & 3)];
        if (lane8 == 0) {
            *reinterpret_cast<float2*>(&out_bidx[(size_t)e * 2]) =
                make_float2((float)bidx[s], (float)bidx[d]);
        } else if (lane8 == 1) {
            const float dd = p + bias_d;                 // z0 - z1
            const float ad = fabsf(dd);
            const float t = -log1pf(expf(-ad));
            const float2 pr = (dd >= 0.f) ? make_float2(t, t - ad) : make_float2(t - ad, t);
            *reinterpret_cast<float2*>(&out_probs[(size_t)e * 2]) = pr;
        }

        if (!more) break;
        e = e2; s = s2; d = d2; ua = ua2; va = va2;
    }
}

extern "C" void kernel_launch(void* const* d_in, const int* in_sizes, int n_in,
                              void* d_out, int out_size, void* d_ws, size_t ws_size,
                              hipStream_t stream) {
    const float* feat   = (const float*)d_in[0];
    const float* bboxes = (const float*)d_in[1];
    const int*   bidx   = (const int*)d_in[2];
    const int*   eidx   = (const int*)d_in[3];
    const float* W1     = (const float*)d_in[4];
    const float* b1     = (const float*)d_in[5];
    const float* W2     = (const float*)d_in[6];
    const float* b2     = (const float*)d_in[7];
    const float* lin1W  = (const float*)d_in[8];
    const float* lin1b  = (const float*)d_in[9];
    const float* linfW  = (const float*)d_in[10];
    const float* linfb  = (const float*)d_in[11];

    const int N = in_sizes[0] / 8;
    const int E = in_sizes[3] / 2;
    const int* row = eidx;        // sources
    const int* col = eidx + E;    // targets

    size_t Np = ((size_t)N + 255) & ~255ull;
    size_t Ep = ((size_t)E + 255) & ~255ull;
    size_t A8 = (((size_t)N * 8) + 255) & ~255ull;
    int*    cnt    = (int*)d_ws;                 // Np
    int*    cursor = cnt + Np;                   // Np (zeroed with cnt)
    int*    ptr    = cursor + Np;                // Np+256
    int*    bsum   = ptr + Np + 256;             // 256
    int2*   eadj   = (int2*)(bsum + 256);        // Ep int2 (src, norm-bits)
    float*  aggF   = (float*)(eadj + Ep);        // A8 f32
    ushort* x1     = (ushort*)(aggF + A8);       // N*128 bf16 (re-used as xbf)
    ushort* h2     = x1 + (size_t)N * 128;       // N*128 bf16
    uchar*  uvbuf  = (uchar*)(h2 + (size_t)N * 128);   // N*256 fp8
    ushort* Wuv    = (ushort*)(uvbuf + (size_t)N * 256); // 256*128 bf16
    ushort* W2t    = Wuv + 256 * 128;            // 128*128 bf16
    ushort* xbf    = x1;                         // alias: x1 dead after k_gemm2

    float* out       = (float*)d_out;
    float* out_probs = out;                   // E*2
    float* out_bbox  = out + (size_t)E * 2;   // E*8
    float* out_bidx  = out + (size_t)E * 10;  // E*2

    const int total = N * 128;
    const int B = 256;
    const int nchunk = (N + 2047) / 2048;

    // CSR build + weight prep
    hipMemsetAsync(cnt, 0, 2 * Np * sizeof(int), stream);   // cnt + cursor
    k_hist<<<(E + B - 1) / B, B, 0, stream>>>(col, cnt, E);
    k_bsum<<<nchunk, 1024, 0, stream>>>(cnt, bsum, N);
    k_scanw<<<nchunk, 1024, 0, stream>>>(cnt, bsum, ptr, N, E);
    k_fill<<<(E + B - 1) / B, B, 0, stream>>>(row, col, cnt, ptr, cursor, eadj, E);
    k_prepWuv<<<(256 * 128 + B - 1) / B, B, 0, stream>>>(lin1W, Wuv);
    k_prepW2<<<(128 * 128 + B - 1) / B, B, 0, stream>>>(W2, W2t);

    // layer 1 (aggregate-first on [N,8], then tiny GEMM)
    k_agg8<<<(N + 31) / 32, B, 0, stream>>>(feat, cnt, ptr, eadj, aggF, N);
    k_gemm1<<<(total + B - 1) / B, B, 0, stream>>>(aggF, W1, b1, x1, total);

    // layer 2 (MFMA GEMM, then 16-lane gather; xbf aliases x1)
    k_gemm2<<<(N + 63) / 64, B, 0, stream>>>(x1, W2t, h2, N);
    k_gather2<<<(N + 15) / 16, B, 0, stream>>>(h2, cnt, ptr, eadj, b2, xbf, N);

    // per-node edge-MLP projections: uv = fp8(xbf @ [W_top|W_bot]), bias folded into u
    k_gemm_uv<<<(N + 63) / 64, 512, 0, stream>>>(xbf, Wuv, lin1b, uvbuf, N);

    // per-edge epilogue + outputs (8 lanes/edge, pipelined)
    k_edge_lite<<<2048, B, 0, stream>>>(uvbuf, linfW, linfb,
                                        bboxes, bidx, row, col,
                                        out_probs, out_bbox, out_bidx, E);
}

// Round 15
// 219.149 us; speedup vs baseline: 1.8443x; 1.1321x over previous
//
#include <hip/hip_runtime.h>
#include <hip/hip_bf16.h>
#include <math.h>

// N=50000 nodes, E=800000 edges, D=128, F_IN=8, C=2
// Output float32: [probs E*2 | bbox_pairs E*8 | bbox_index_pairs E*2]

typedef __attribute__((ext_vector_type(8))) short short8;
typedef __attribute__((ext_vector_type(4))) float f32x4;
typedef __attribute__((ext_vector_type(2))) float fv2;

__device__ inline ushort f2bf(float f) {
    union { __hip_bfloat16 h; ushort u; } cv;
    cv.h = __float2bfloat16(f);
    return cv.u;
}
__device__ inline float bf2f(ushort u) {
    union { float f; uint u; } c;
    c.u = ((uint)u) << 16;
    return c.f;
}
__device__ inline uchar f2fp8(float f) {
    // OCP e4m3 via HW pack (low byte of packed pair)
    uint p = __builtin_amdgcn_cvt_pk_fp8_f32(f, f, 0u, false);
    return (uchar)(p & 0xffu);
}

// ---------------- CSR build ----------------
__global__ void k_hist(const int* __restrict__ col, int* __restrict__ cnt, int E) {
    int e = blockIdx.x * blockDim.x + threadIdx.x;
    if (e < E) atomicAdd(&cnt[col[e]], 1);
}

__global__ __launch_bounds__(1024) void k_bsum(const int* __restrict__ cnt,
                                               int* __restrict__ bsum, int N) {
    __shared__ int ts[1024];
    const int b = blockIdx.x, t = threadIdx.x;
    const int i0 = b * 2048 + 2 * t;
    int a0 = (i0 < N) ? cnt[i0] : 0;
    int a1 = (i0 + 1 < N) ? cnt[i0 + 1] : 0;
    ts[t] = a0 + a1;
    __syncthreads();
#pragma unroll
    for (int off = 512; off > 0; off >>= 1) {
        if (t < off) ts[t] += ts[t + off];
        __syncthreads();
    }
    if (t == 0) bsum[b] = ts[0];
}

__global__ __launch_bounds__(1024) void k_scanw(const int* __restrict__ cnt,
                                                const int* __restrict__ bsum,
                                                int* __restrict__ ptr, int N, int E) {
    __shared__ int ts[1024];
    const int b = blockIdx.x, t = threadIdx.x;
    int boff = 0;
    for (int i = 0; i < b; ++i) boff += bsum[i];
    const int i0 = b * 2048 + 2 * t;
    const int a0 = (i0 < N) ? cnt[i0] : 0;
    const int a1 = (i0 + 1 < N) ? cnt[i0 + 1] : 0;
    const int s = a0 + a1;
    ts[t] = s;
    __syncthreads();
    for (int off = 1; off < 1024; off <<= 1) {
        int v = (t >= off) ? ts[t - off] : 0;
        __syncthreads();
        ts[t] += v;
        __syncthreads();
    }
    const int excl = boff + ts[t] - s;
    if (i0 < N) ptr[i0] = excl;
    if (i0 + 1 < N) ptr[i0 + 1] = excl + a0;
    if (b == 0 && t == 0) ptr[N] = E;
}

__global__ void k_fill(const int* __restrict__ row, const int* __restrict__ col,
                       const int* __restrict__ cnt, const int* __restrict__ ptr,
                       int* __restrict__ cursor, int2* __restrict__ eadj, int E) {
    int e = blockIdx.x * blockDim.x + threadIdx.x;
    if (e >= E) return;
    int r = row[e], c = col[e];
    float dr = rsqrtf(1.0f + (float)cnt[r]);
    float dc = rsqrtf(1.0f + (float)cnt[c]);
    int p = ptr[c] + atomicAdd(&cursor[c], 1);
    eadj[p] = make_int2(r, __float_as_int(dr * dc));
}

// ---------------- weight prep (fused) ----------------
// Wuv[c][k]: c<128: lin1W[k][c]; c>=128: lin1W[128+k][c-128].  W2t[n][k] = W2[k][n].
__global__ void k_prepW(const float* __restrict__ lin1W, const float* __restrict__ W2,
                        ushort* __restrict__ Wuv, ushort* __restrict__ W2t) {
    int tid = blockIdx.x * blockDim.x + threadIdx.x;
    if (tid < 256 * 128) {
        int c = tid >> 7, k = tid & 127;
        int krow = k + ((c >> 7) << 7);
        Wuv[tid] = f2bf(lin1W[krow * 128 + (c & 127)]);
    } else if (tid < 256 * 128 + 128 * 128) {
        int u = tid - 256 * 128;
        int n = u >> 7, k = u & 127;
        W2t[u] = f2bf(W2[k * 128 + n]);
    }
}

// ---------------- fused layer-1: aggregate [N,8] in LDS + GEMM -> x1 bf16 ----------------
// Block 256 thr = 32 nodes. Phase 1: 8 lanes/node aggregate. Phase 2: 8 thr/node x 16 cols.
__global__ __launch_bounds__(256) void k_l1(const float* __restrict__ feat,
                                            const int* __restrict__ cnt,
                                            const int* __restrict__ ptr,
                                            const int2* __restrict__ eadj,
                                            const float* __restrict__ W1,
                                            const float* __restrict__ b1,
                                            ushort* __restrict__ x1, int N) {
    __shared__ float sagg[32][8];
    __shared__ float sW1[8 * 128];
    const int tid = threadIdx.x;
    for (int i = tid; i < 1024; i += 256) sW1[i] = W1[i];

    const int lane8 = tid & 7;
    const int nloc = tid >> 3;
    const int node = blockIdx.x * 32 + nloc;
    float acc = 0.f;
    if (node < N) {
        float dd = 1.0f / (1.0f + (float)cnt[node]);
        acc = feat[(size_t)node * 8 + lane8] * dd;
        int i = ptr[node], end = ptr[node + 1];
        for (; i < end; ++i) {
            const int2 a = eadj[i];
            acc += feat[(size_t)a.x * 8 + lane8] * __int_as_float(a.y);
        }
    }
    sagg[nloc][lane8] = acc;
    __syncthreads();

    if (node < N) {
        const int jb = lane8 * 16;
        float av[8];
#pragma unroll
        for (int k = 0; k < 8; ++k) av[k] = sagg[nloc][k];
        short8 r0, r1;
#pragma unroll
        for (int j = 0; j < 16; ++j) {
            float s = b1[jb + j];
#pragma unroll
            for (int k = 0; k < 8; ++k) s = fmaf(av[k], sW1[k * 128 + jb + j], s);
            const ushort bv = f2bf(fmaxf(s, 0.f));
            if (j < 8) r0[j] = (short)bv; else r1[j - 8] = (short)bv;
        }
        *reinterpret_cast<short8*>(&x1[(size_t)node * 128 + jb]) = r0;
        *reinterpret_cast<short8*>(&x1[(size_t)node * 128 + jb + 8]) = r1;
    }
}

// ---------------- layer-2 GEMM via MFMA: h2 = fp8(x1[N,128] @ W2) ----------------
// Block: 256 thr = 4 waves, 64 nodes. Wave: 16 nodes x 128 cols, K=128.  (proven R5 shape)
__global__ __launch_bounds__(256) void k_gemm2(const ushort* __restrict__ x1,
                                               const ushort* __restrict__ W2t,
                                               uchar* __restrict__ h2, int N) {
    __shared__ ushort ldsW[128 * 128];   // 32 KB, XOR-swizzled (256B rows)
    const int tid = threadIdx.x;
    const int wave = tid >> 6, lane = tid & 63;
    const int m = lane & 15, kb = lane >> 4;
    const int n0 = blockIdx.x * 64;

    const int node_a = min(n0 + wave * 16 + m, N - 1);
    short8 a[4];
#pragma unroll
    for (int kk = 0; kk < 4; ++kk) {
        a[kk] = *reinterpret_cast<const short8*>(&x1[(size_t)node_a * 128 + kk * 32 + kb * 8]);
    }

    {
        char* lb = reinterpret_cast<char*>(ldsW);
        const short8* wg = reinterpret_cast<const short8*>(W2t);
#pragma unroll
        for (int i = 0; i < 8; ++i) {
            const int g = i * 256 + tid;
            const int bo = g * 16;
            const int swz = bo ^ (((bo >> 8) & 7) << 4);
            *reinterpret_cast<short8*>(lb + swz) = wg[g];
        }
    }
    __syncthreads();

    f32x4 acc[8];
#pragma unroll
    for (int t = 0; t < 8; ++t) acc[t] = (f32x4){0.f, 0.f, 0.f, 0.f};

    const char* lbr = reinterpret_cast<const char*>(ldsW);
    const int mswz = (m & 7) << 4;
#pragma unroll
    for (int kk = 0; kk < 4; ++kk) {
#pragma unroll
        for (int t = 0; t < 8; ++t) {
            const int bo = (t * 16 + m) * 256 + kk * 64 + kb * 16;
            const short8 b = *reinterpret_cast<const short8*>(lbr + (bo ^ mswz));
            acc[t] = __builtin_amdgcn_mfma_f32_16x16x32_bf16(a[kk], b, acc[t], 0, 0, 0);
        }
    }

#pragma unroll
    for (int r = 0; r < 4; ++r) {
        const int node = n0 + wave * 16 + kb * 4 + r;
        if (node < N) {
#pragma unroll
            for (int t = 0; t < 8; ++t) {
                h2[(size_t)node * 128 + t * 16 + m] = f2fp8(acc[t][r]);
            }
        }
    }
}

// ---------------- layer-2 aggregate over fp8 h2: 8 lanes/node, uint4 rows ----------------
__global__ __launch_bounds__(256) void k_gather2(const uchar* __restrict__ h2,
                                                 const int* __restrict__ cnt,
                                                 const int* __restrict__ ptr,
                                                 const int2* __restrict__ eadj,
                                                 const float* __restrict__ b2,
                                                 ushort* __restrict__ xbf, int N) {
    const int lane8 = threadIdx.x & 7;
    const int node = blockIdx.x * 32 + (threadIdx.x >> 3);
    if (node >= N) return;
    const float dd = 1.0f / (1.0f + (float)cnt[node]);
    float acc[16];
    {
        const uint4 w = *reinterpret_cast<const uint4*>(&h2[(size_t)node * 128 + lane8 * 16]);
        const uint ws[4] = {w.x, w.y, w.z, w.w};
#pragma unroll
        for (int q = 0; q < 4; ++q) {
            const fv2 lo = __builtin_amdgcn_cvt_pk_f32_fp8(ws[q], false);
            const fv2 hi = __builtin_amdgcn_cvt_pk_f32_fp8(ws[q], true);
            acc[4 * q + 0] = lo[0] * dd;
            acc[4 * q + 1] = lo[1] * dd;
            acc[4 * q + 2] = hi[0] * dd;
            acc[4 * q + 3] = hi[1] * dd;
        }
    }
    int i = ptr[node];
    const int end = ptr[node + 1];
    for (; i < end; ++i) {
        const int2 aa = eadj[i];
        const float nm = __int_as_float(aa.y);
        const uint4 w = *reinterpret_cast<const uint4*>(&h2[(size_t)aa.x * 128 + lane8 * 16]);
        const uint ws[4] = {w.x, w.y, w.z, w.w};
#pragma unroll
        for (int q = 0; q < 4; ++q) {
            const fv2 lo = __builtin_amdgcn_cvt_pk_f32_fp8(ws[q], false);
            const fv2 hi = __builtin_amdgcn_cvt_pk_f32_fp8(ws[q], true);
            acc[4 * q + 0] = fmaf(lo[0], nm, acc[4 * q + 0]);
            acc[4 * q + 1] = fmaf(lo[1], nm, acc[4 * q + 1]);
            acc[4 * q + 2] = fmaf(hi[0], nm, acc[4 * q + 2]);
            acc[4 * q + 3] = fmaf(hi[1], nm, acc[4 * q + 3]);
        }
    }
    short8 r0, r1;
#pragma unroll
    for (int q = 0; q < 8; ++q) {
        r0[q] = (short)f2bf(fmaxf(acc[q] + b2[lane8 * 16 + q], 0.f));
        r1[q] = (short)f2bf(fmaxf(acc[8 + q] + b2[lane8 * 16 + 8 + q], 0.f));
    }
    *reinterpret_cast<short8*>(&xbf[(size_t)node * 128 + lane8 * 16]) = r0;
    *reinterpret_cast<short8*>(&xbf[(size_t)node * 128 + lane8 * 16 + 8]) = r1;
}

// ---------------- uv GEMM via MFMA: uv[N,256] = fp8(xbf[N,128] @ Wuv^T); bias folded into u ----------------
// Block: 512 thr = 8 waves, 64 nodes. Wave: 16 nodes x 128-col half, K=128.
__global__ __launch_bounds__(512) void k_gemm_uv(const ushort* __restrict__ xbf,
                                                 const ushort* __restrict__ Wuv,
                                                 const float* __restrict__ lin1b,
                                                 uchar* __restrict__ uv, int N) {
    __shared__ ushort ldsW[256 * 128];   // 64 KB, XOR-swizzled (256B rows)
    const int tid = threadIdx.x;
    const int wave = tid >> 6, lane = tid & 63;
    const int m = lane & 15, kb = lane >> 4;
    const int ng = wave >> 1;            // node group 0..3
    const int ch = wave & 1;             // col half 0..1 (0 = u, 1 = v)
    const int n0 = blockIdx.x * 64 + ng * 16;

    const int node_a = min(n0 + m, N - 1);
    short8 a[4];
#pragma unroll
    for (int kk = 0; kk < 4; ++kk) {
        a[kk] = *reinterpret_cast<const short8*>(&xbf[(size_t)node_a * 128 + kk * 32 + kb * 8]);
    }

    {
        char* lb = reinterpret_cast<char*>(ldsW);
        const short8* wg = reinterpret_cast<const short8*>(Wuv);
#pragma unroll
        for (int i = 0; i < 8; ++i) {
            const int g = i * 512 + tid;
            const int bo = g * 16;
            const int swz = bo ^ (((bo >> 8) & 7) << 4);
            *reinterpret_cast<short8*>(lb + swz) = wg[g];
        }
    }
    __syncthreads();

    f32x4 acc[8];
#pragma unroll
    for (int t = 0; t < 8; ++t) acc[t] = (f32x4){0.f, 0.f, 0.f, 0.f};

    const char* lbr = reinterpret_cast<const char*>(ldsW);
    const int mswz = (m & 7) << 4;
#pragma unroll
    for (int kk = 0; kk < 4; ++kk) {
#pragma unroll
        for (int t = 0; t < 8; ++t) {
            const int bo = (ch * 128 + t * 16 + m) * 256 + kk * 64 + kb * 16;
            const short8 b = *reinterpret_cast<const short8*>(lbr + (bo ^ mswz));
            acc[t] = __builtin_amdgcn_mfma_f32_16x16x32_bf16(a[kk], b, acc[t], 0, 0, 0);
        }
    }

    // C layout: col = ch*128 + t*16 + m, row(node) = kb*4 + r. u-half gets +lin1b.
#pragma unroll
    for (int r = 0; r < 4; ++r) {
        const int node = n0 + kb * 4 + r;
        if (node < N) {
#pragma unroll
            for (int t = 0; t < 8; ++t) {
                const int c = t * 16 + m;
                float av = acc[t][r];
                if (ch == 0) av += lin1b[c];
                uv[(size_t)node * 256 + ch * 128 + c] = f2fp8(av);
            }
        }
    }
}

// ---------------- edge kernel: 8 lanes/edge, uint4 gathers, 2-deep pipeline ----------------
__global__ __launch_bounds__(256) void k_edge_lite(const uchar* __restrict__ uv,
                                                   const float* __restrict__ linfW,
                                                   const float* __restrict__ linfb,
                                                   const float* __restrict__ bboxes,
                                                   const int* __restrict__ bidx,
                                                   const int* __restrict__ row,
                                                   const int* __restrict__ col,
                                                   float* __restrict__ out_probs,
                                                   float* __restrict__ out_bbox,
                                                   float* __restrict__ out_bidx,
                                                   int E) {
    const int lane8 = threadIdx.x & 7;
    const int slot = threadIdx.x >> 3;       // 32 edges per 256-thr block iteration
    int e = blockIdx.x * 32 + slot;
    if (e >= E) return;

    float wd[16];
#pragma unroll
    for (int j = 0; j < 16; ++j) {
        const int c = lane8 * 16 + j;
        wd[j] = linfW[c * 2] - linfW[c * 2 + 1];
    }
    const float bias_d = linfb[0] - linfb[1];
    const int step = gridDim.x * 32;

    int s = row[e], d = col[e];
    uint4 ua = *reinterpret_cast<const uint4*>(&uv[(size_t)s * 256 + lane8 * 16]);
    uint4 va = *reinterpret_cast<const uint4*>(&uv[(size_t)d * 256 + 128 + lane8 * 16]);

    while (true) {
        const int e2 = e + step;
        const bool more = (e2 < E);
        int s2 = 0, d2 = 0;
        uint4 ua2 = ua, va2 = va;
        if (more) {
            s2 = row[e2];
            d2 = col[e2];
            ua2 = *reinterpret_cast<const uint4*>(&uv[(size_t)s2 * 256 + lane8 * 16]);
            va2 = *reinterpret_cast<const uint4*>(&uv[(size_t)d2 * 256 + 128 + lane8 * 16]);
        }

        float p = 0.f;
        {
            const uint uw[4] = {ua.x, ua.y, ua.z, ua.w};
            const uint vw[4] = {va.x, va.y, va.z, va.w};
#pragma unroll
            for (int w = 0; w < 4; ++w) {
                const fv2 ul = __builtin_amdgcn_cvt_pk_f32_fp8(uw[w], false);
                const fv2 uh = __builtin_amdgcn_cvt_pk_f32_fp8(uw[w], true);
                const fv2 vl = __builtin_amdgcn_cvt_pk_f32_fp8(vw[w], false);
                const fv2 vh = __builtin_amdgcn_cvt_pk_f32_fp8(vw[w], true);
                p = fmaf(fmaxf(ul[0] + vl[0], 0.f), wd[4 * w + 0], p);
                p = fmaf(fmaxf(ul[1] + vl[1], 0.f), wd[4 * w + 1], p);
                p = fmaf(fmaxf(uh[0] + vh[0], 0.f), wd[4 * w + 2], p);
                p = fmaf(fmaxf(uh[1] + vh[1], 0.f), wd[4 * w + 3], p);
            }
        }
        p += __shfl_xor(p, 1);
        p += __shfl_xor(p, 2);
        p += __shfl_xor(p, 4);

        out_bbox[(size_t)e * 8 + lane8] = bboxes[(size_t)((lane8 < 4) ? s : d) * 4 + (lane8 & 3)];
        if (lane8 == 0) {
            *reinterpret_cast<float2*>(&out_bidx[(size_t)e * 2]) =
                make_float2((float)bidx[s], (float)bidx[d]);
        } else if (lane8 == 1) {
            const float dd = p + bias_d;                 // z0 - z1
            const float ad = fabsf(dd);
            const float t = -log1pf(expf(-ad));
            const float2 pr = (dd >= 0.f) ? make_float2(t, t - ad) : make_float2(t - ad, t);
            *reinterpret_cast<float2*>(&out_probs[(size_t)e * 2]) = pr;
        }

        if (!more) break;
        e = e2; s = s2; d = d2; ua = ua2; va = va2;
    }
}

extern "C" void kernel_launch(void* const* d_in, const int* in_sizes, int n_in,
                              void* d_out, int out_size, void* d_ws, size_t ws_size,
                              hipStream_t stream) {
    const float* feat   = (const float*)d_in[0];
    const float* bboxes = (const float*)d_in[1];
    const int*   bidx   = (const int*)d_in[2];
    const int*   eidx   = (const int*)d_in[3];
    const float* W1     = (const float*)d_in[4];
    const float* b1     = (const float*)d_in[5];
    const float* W2     = (const float*)d_in[6];
    const float* b2     = (const float*)d_in[7];
    const float* lin1W  = (const float*)d_in[8];
    const float* lin1b  = (const float*)d_in[9];
    const float* linfW  = (const float*)d_in[10];
    const float* linfb  = (const float*)d_in[11];

    const int N = in_sizes[0] / 8;
    const int E = in_sizes[3] / 2;
    const int* row = eidx;        // sources
    const int* col = eidx + E;    // targets

    size_t Np = ((size_t)N + 255) & ~255ull;
    size_t Ep = ((size_t)E + 255) & ~255ull;
    int*    cnt    = (int*)d_ws;                 // Np
    int*    cursor = cnt + Np;                   // Np (zeroed with cnt)
    int*    ptr    = cursor + Np;                // Np+256
    int*    bsum   = ptr + Np + 256;             // 256
    int2*   eadj   = (int2*)(bsum + 256);        // Ep int2 (src, norm-bits)
    ushort* x1     = (ushort*)(eadj + Ep);       // N*128 bf16 (re-used as xbf)
    uchar*  h2     = (uchar*)(x1 + (size_t)N * 128);   // N*128 fp8
    uchar*  uvbuf  = h2 + (size_t)N * 128;       // N*256 fp8
    ushort* Wuv    = (ushort*)(uvbuf + (size_t)N * 256); // 256*128 bf16
    ushort* W2t    = Wuv + 256 * 128;            // 128*128 bf16
    ushort* xbf    = x1;                         // alias: x1 dead after k_gemm2

    float* out       = (float*)d_out;
    float* out_probs = out;                   // E*2
    float* out_bbox  = out + (size_t)E * 2;   // E*8
    float* out_bidx  = out + (size_t)E * 10;  // E*2

    const int B = 256;
    const int nchunk = (N + 2047) / 2048;

    // CSR build + weight prep
    hipMemsetAsync(cnt, 0, 2 * Np * sizeof(int), stream);   // cnt + cursor
    k_hist<<<(E + B - 1) / B, B, 0, stream>>>(col, cnt, E);
    k_bsum<<<nchunk, 1024, 0, stream>>>(cnt, bsum, N);
    k_scanw<<<nchunk, 1024, 0, stream>>>(cnt, bsum, ptr, N, E);
    k_fill<<<(E + B - 1) / B, B, 0, stream>>>(row, col, cnt, ptr, cursor, eadj, E);
    k_prepW<<<(256 * 128 + 128 * 128 + B - 1) / B, B, 0, stream>>>(lin1W, W2, Wuv, W2t);

    // layer 1 fused (aggregate + GEMM)
    k_l1<<<(N + 31) / 32, B, 0, stream>>>(feat, cnt, ptr, eadj, W1, b1, x1, N);

    // layer 2 (MFMA GEMM -> fp8 h2, then 8-lane fp8 gather; xbf aliases x1)
    k_gemm2<<<(N + 63) / 64, B, 0, stream>>>(x1, W2t, h2, N);
    k_gather2<<<(N + 31) / 32, B, 0, stream>>>(h2, cnt, ptr, eadj, b2, xbf, N);

    // per-node edge-MLP projections: uv = fp8(xbf @ [W_top|W_bot]), bias folded into u
    k_gemm_uv<<<(N + 63) / 64, 512, 0, stream>>>(xbf, Wuv, lin1b, uvbuf, N);

    // per-edge epilogue + outputs (8 lanes/edge, pipelined)
    k_edge_lite<<<2048, B, 0, stream>>>(uvbuf, linfW, linfb,
                                        bboxes, bidx, row, col,
                                        out_probs, out_bbox, out_bidx, E);
}